// Round 28
// baseline (198.823 us; speedup 1.0000x reference)
//
#include <hip/hip_runtime.h>
#include <hip/hip_fp16.h>
#include <cstdint>
#include <cstddef>

typedef _Float16 f16x8 __attribute__((ext_vector_type(8)));
typedef float f32x4 __attribute__((ext_vector_type(4)));

__device__ __forceinline__ float exp_am8(float a) {
    return __builtin_amdgcn_exp2f(fmaf(a, 1.442695040888963f, -11.541560327111707f));
}

// ================= prep (fused): pack_w2 (blocks 0..127) + decoder_prep3 (128) + zero (129)
__global__ void prep_all(
    const float* __restrict__ Wa0, const float* __restrict__ Wb0, _Float16* __restrict__ P0,
    const float* __restrict__ Wa1, const float* __restrict__ Wb1, _Float16* __restrict__ P1,
    const float* __restrict__ Wd1, const float* __restrict__ bd1,
    const float* __restrict__ Wd2, const float* __restrict__ bd2,
    const float* __restrict__ b2_cm, const float* __restrict__ b2_mc,
    const float* __restrict__ W2s_mc, const float* __restrict__ a2s_mc,
    const float* __restrict__ W2d_cm, const float* __restrict__ a2d_cm,
    const float* __restrict__ W2s_cm, const float* __restrict__ a2s_cm,
    const float* __restrict__ W2d_mc, const float* __restrict__ a2d_mc,
    float* __restrict__ Wc, float* __restrict__ bc, float* __restrict__ bq,
    float4* __restrict__ foldA, float4* __restrict__ foldB,
    int* __restrict__ bcnt_base) {
    __shared__ float WcS[256];
    int b = blockIdx.x;
    int t = threadIdx.x;
    if (b < 128) {
        const float* Wa; const float* Wb; _Float16* Wp; int lb;
        if (b < 64) { Wa = Wa0; Wb = Wb0; Wp = P0; lb = b; }
        else        { Wa = Wa1; Wb = Wb1; Wp = P1; lb = b - 64; }
        constexpr int K = 128;
        constexpr int NKB = K / 32;
        int i = lb * 256 + t;
        if (i >= 128 * K) return;
        int k = i >> 7, c = i & 127;
        float v = (c < 64) ? Wa[k * 64 + c] : Wb[k * 64 + (c - 64)];
        int ct = c >> 4, lr = c & 15, kb = k >> 5, lk = (k & 31) >> 3, e = k & 7;
        Wp[((ct * NKB + kb) * 64 + (lr + 16 * lk)) * 8 + e] = (_Float16)v;
    } else if (b == 128) {
        int k = t >> 1, c = t & 1;
        float s = 0.f;
        for (int j = 0; j < 64; ++j) s += Wd1[k * 64 + j] * Wd2[j * 2 + c];
        Wc[k * 2 + c] = s;
        WcS[k * 2 + c] = s;
        if (k == 0) {
            float bv = bd2[c];
            for (int j = 0; j < 64; ++j) bv += bd1[j] * Wd2[j * 2 + c];
            bc[c] = bv;
        }
        __syncthreads();
        if (t < 2) {
            float v = 0.f;
            for (int j = 0; j < 64; ++j) v += b2_cm[j] * WcS[j * 2 + t];
            bq[t] = v;
        } else if (t < 4) {
            int cc = t - 2;
            float v = 0.f;
            for (int j = 0; j < 64; ++j) v += b2_mc[j] * WcS[(64 + j) * 2 + cc];
            bq[t] = v;
        }
        if (t < 64) {
            int j = t;
            float fa = 0.f, fd = 0.f, qx = 0.f, qy = 0.f;
            for (int cc = 0; cc < 64; ++cc) {
                float ws = W2s_mc[j * 64 + cc];
                fa += ws * a2s_mc[cc];
                qx += ws * WcS[(64 + cc) * 2 + 0];
                qy += ws * WcS[(64 + cc) * 2 + 1];
                fd += W2d_cm[j * 64 + cc] * a2d_cm[cc];
            }
            foldA[j] = make_float4(fa, fd, qx, qy);
        } else if (t < 128) {
            int j = t - 64;
            float fa = 0.f, fd = 0.f, qx = 0.f, qy = 0.f;
            for (int cc = 0; cc < 64; ++cc) {
                float ws = W2s_cm[j * 64 + cc];
                fa += ws * a2s_cm[cc];
                qx += ws * WcS[cc * 2 + 0];
                qy += ws * WcS[cc * 2 + 1];
                fd += W2d_mc[j * 64 + cc] * a2d_mc[cc];
            }
            foldB[j] = make_float4(fa, fd, qx, qy);
        }
    } else {
        bcnt_base[t] = 0;
        bcnt_base[t + 256] = 0;
    }
}

// ========== proj body v2 (512 thr, 128 rows): coalesced X staging via LDS ==========
#define XPAD 72

__device__ __forceinline__ void proj_body(const float* __restrict__ X, int N,
                                          const _Float16* __restrict__ Wp,
                                          const float* __restrict__ a0v,
                                          const float* __restrict__ a1v,
                                          __half* __restrict__ out0,
                                          float* __restrict__ al0,
                                          float* __restrict__ al1,
                                          char* smem, int blk) {
    constexpr int K = 128;
    _Float16* Wlds = (_Float16*)smem;
    _Float16* Xs = (_Float16*)(smem + 32768);   // [128][XPAD]
    int t = threadIdx.x;
    constexpr int NV = (128 * K) / 8;
#pragma unroll
    for (int i = t; i < NV; i += 512)
        ((uint4*)Wlds)[i] = ((const uint4*)Wp)[i];

    int rt = blk * 128;
    int wv = t >> 6, lane = t & 63, lr = lane & 15, lk = lane >> 4;
    int row = rt + wv * 16 + lr;
    int xrow = t >> 4;
    int xcp = t & 15;

    f32x4 acc[8];
#pragma unroll
    for (int i = 0; i < 8; ++i) acc[i] = f32x4{0.f, 0.f, 0.f, 0.f};

    const f16x8* Wf = (const f16x8*)Wlds;
#pragma unroll
    for (int half = 0; half < 2; ++half) {
        __syncthreads();
#pragma unroll
        for (int pass = 0; pass < 4; ++pass) {
            int r = pass * 32 + xrow;
            int grow = rt + r;
            if (grow >= N) grow = N - 1;
            float4 v = *(const float4*)(X + (size_t)grow * K + half * 64 + xcp * 4);
            __half2 h01 = __floats2half2_rn(v.x, v.y);
            __half2 h23 = __floats2half2_rn(v.z, v.w);
            uint2 pk;
            pk.x = *(const unsigned int*)&h01;
            pk.y = *(const unsigned int*)&h23;
            *(uint2*)&Xs[r * XPAD + xcp * 4] = pk;
        }
        __syncthreads();
#pragma unroll
        for (int kb = 0; kb < 2; ++kb) {
            f16x8 bf = *(const f16x8*)&Xs[(wv * 16 + lr) * XPAD + kb * 32 + lk * 8];
            int kbb = half * 2 + kb;
#pragma unroll
            for (int ct = 0; ct < 8; ++ct) {
                acc[ct] = __builtin_amdgcn_mfma_f32_16x16x32_f16(
                    Wf[(ct * 4 + kbb) * 64 + lane], bf, acc[ct], 0, 0, 0);
            }
        }
    }

    float p0 = 0.f, p1 = 0.f;
#pragma unroll
    for (int ct = 0; ct < 4; ++ct) {
        float4 aq = ((const float4*)a0v)[ct * 4 + lk];
        f32x4 v = acc[ct];
        p0 += v[0] * aq.x + v[1] * aq.y + v[2] * aq.z + v[3] * aq.w;
    }
#pragma unroll
    for (int ct = 0; ct < 4; ++ct) {
        float4 aq = ((const float4*)a1v)[ct * 4 + lk];
        f32x4 v = acc[4 + ct];
        p1 += v[0] * aq.x + v[1] * aq.y + v[2] * aq.z + v[3] * aq.w;
    }
    p0 += __shfl_xor(p0, 16); p0 += __shfl_xor(p0, 32);
    p1 += __shfl_xor(p1, 16); p1 += __shfl_xor(p1, 32);
    if (row < N) {
#pragma unroll
        for (int ct = 0; ct < 4; ++ct) {
            f32x4 v = acc[ct];
            __half2 h01 = __floats2half2_rn(v[0], v[1]);
            __half2 h23 = __floats2half2_rn(v[2], v[3]);
            uint2 pk;
            pk.x = *(const unsigned int*)&h01;
            pk.y = *(const unsigned int*)&h23;
            *(uint2*)(out0 + ((size_t)row << 6) + ct * 16 + lk * 4) = pk;
        }
        if (lane < 16) { al0[row] = p0; al1[row] = p1; }
    }
}

// ========== fused launch (512 thr): proj_m | proj_c | bucket_hist ==========
__global__ __launch_bounds__(512) void fused_proj_hist(
    const float* __restrict__ Xm, int Nm, const _Float16* __restrict__ WpA,
    const float* __restrict__ a0A, const float* __restrict__ a1A,
    __half* __restrict__ outA, float* __restrict__ al0A, float* __restrict__ al1A, int nbm,
    const float* __restrict__ Xc, int Nc, const _Float16* __restrict__ WpB,
    const float* __restrict__ a0B, const float* __restrict__ a1B,
    __half* __restrict__ outB, float* __restrict__ al0B, float* __restrict__ al1B, int nbc,
    const int* __restrict__ dmc, int* __restrict__ bcnt_mc, int shA,
    const int* __restrict__ dcm, int* __restrict__ bcnt_cm, int shB, int E, int nblk) {
    extern __shared__ __align__(16) char smem[];
    int b = blockIdx.x;
    if (b < nbm) {
        proj_body(Xm, Nm, WpA, a0A, a1A, outA, al0A, al1A, smem, b);
        return;
    }
    b -= nbm;
    if (b < nbc) {
        proj_body(Xc, Nc, WpB, a0B, a1B, outB, al0B, al1B, smem, b);
        return;
    }
    b -= nbc;
    int* h = (int*)smem;
    const int* dst; int* bcnt; int sh; int base;
    if (b < nblk) { dst = dmc; bcnt = bcnt_mc; sh = shA; base = b * 4096; }
    else { dst = dcm; bcnt = bcnt_cm; sh = shB; base = (b - nblk) * 4096; }
    int t = threadIdx.x;
    if (t < 256) h[t] = 0;
    __syncthreads();
#pragma unroll
    for (int j = 0; j < 8; ++j) {
        int i = base + j * 512 + t;
        if (i < E) atomicAdd(&h[dst[i] >> sh], 1);
    }
    __syncthreads();
    if (t < 256) {
        int c = h[t];
        if (c > 0) atomicAdd(&bcnt[t], c);
    }
}

// ================= CSR build tail =================
__global__ void bucket_scan(const int* __restrict__ bcntA, int nbkA,
                            int* __restrict__ bbaseA, int* __restrict__ bcurA,
                            int* __restrict__ offA, int nA,
                            const int* __restrict__ bcntB, int nbkB,
                            int* __restrict__ bbaseB, int* __restrict__ bcurB,
                            int* __restrict__ offB, int nB, int E) {
    int t = threadIdx.x;
    if (t == 0) {
        int run = 0;
        for (int i = 0; i < nbkA; ++i) { bbaseA[i] = run; bcurA[i] = run; run += bcntA[i]; }
        bbaseA[nbkA] = run;
        offA[nA] = E;
    }
    if (t == 64) {
        int run = 0;
        for (int i = 0; i < nbkB; ++i) { bbaseB[i] = run; bcurB[i] = run; run += bcntB[i]; }
        bbaseB[nbkB] = run;
        offB[nB] = E;
    }
}

__global__ __launch_bounds__(256) void bucket_scatter(
    const int* __restrict__ srcA, const int* __restrict__ dstA,
    int* __restrict__ bcurA, unsigned* __restrict__ pairsA,
    const int* __restrict__ srcB, const int* __restrict__ dstB,
    int* __restrict__ bcurB, unsigned* __restrict__ pairsB,
    int E, int nblkA, int shA, int shB, int srcbits) {
    __shared__ int bcnt[256];
    __shared__ int bbase[256];
    const int* src; const int* dst; int* bcur; unsigned* pairs; int sh; int base;
    if ((int)blockIdx.x < nblkA) {
        src = srcA; dst = dstA; bcur = bcurA; pairs = pairsA; sh = shA;
        base = blockIdx.x * 4096;
    } else {
        src = srcB; dst = dstB; bcur = bcurB; pairs = pairsB; sh = shB;
        base = (blockIdx.x - nblkA) * 4096;
    }
    int t = threadIdx.x;
    int msk = (1 << sh) - 1;
    bcnt[t] = 0;
    __syncthreads();
    int sreg[16], dreg[16];
#pragma unroll
    for (int j = 0; j < 16; ++j) {
        int i = base + j * 256 + t;
        if (i < E) {
            sreg[j] = src[i];
            dreg[j] = dst[i];
            atomicAdd(&bcnt[dreg[j] >> sh], 1);
        } else {
            dreg[j] = -1;
        }
    }
    __syncthreads();
    {
        int c = bcnt[t];
        int g = (c > 0) ? atomicAdd(&bcur[t], c) : 0;
        bbase[t] = g;
        bcnt[t] = 0;
    }
    __syncthreads();
#pragma unroll
    for (int j = 0; j < 16; ++j) {
        if (dreg[j] >= 0) {
            int b = dreg[j] >> sh;
            int r = atomicAdd(&bcnt[b], 1);
            pairs[bbase[b] + r] = ((unsigned)(dreg[j] & msk) << srcbits) | (unsigned)sreg[j];
        }
    }
}

__global__ __launch_bounds__(256) void bucket_expand2(
    const unsigned* __restrict__ pairsA, const int* __restrict__ bbaseA, int nA,
    int* __restrict__ offA, int* __restrict__ csrA, int shA, int nbA,
    const unsigned* __restrict__ pairsB, const int* __restrict__ bbaseB, int nB,
    int* __restrict__ offB, int* __restrict__ csrB, int shB, int srcbits) {
    __shared__ int lcnt[1024];
    __shared__ int red[256];
    const unsigned* pairs; const int* bbase; int n; int* off; int* csr; int sh; int b;
    if ((int)blockIdx.x < nbA) {
        pairs = pairsA; bbase = bbaseA; n = nA; off = offA; csr = csrA; sh = shA;
        b = blockIdx.x;
    } else {
        pairs = pairsB; bbase = bbaseB; n = nB; off = offB; csr = csrB; sh = shB;
        b = blockIdx.x - nbA;
    }
    int dpb = 1 << sh;
    int d0 = b << sh;
    int t = threadIdx.x;
    unsigned smask = (1u << srcbits) - 1u;
    for (int dl = t; dl < dpb; dl += 256) lcnt[dl] = 0;
    __syncthreads();
    int pbeg = bbase[b], pend = bbase[b + 1];
    for (int i = pbeg + t; i < pend; i += 256)
        atomicAdd(&lcnt[pairs[i] >> srcbits], 1);
    __syncthreads();
    int per = (dpb + 255) >> 8;
    int i0 = t * per;
    int s = 0;
    for (int j = 0; j < per; ++j) {
        int dl = i0 + j;
        if (dl < dpb) s += lcnt[dl];
    }
    red[t] = s;
    __syncthreads();
    for (int st = 1; st < 256; st <<= 1) {
        int tmp = (t >= st) ? red[t - st] : 0;
        __syncthreads();
        red[t] += tmp;
        __syncthreads();
    }
    int run = pbeg + red[t] - s;
    for (int j = 0; j < per; ++j) {
        int dl = i0 + j;
        if (dl < dpb) {
            int c = lcnt[dl];
            if (d0 + dl < n) off[d0 + dl] = run;
            lcnt[dl] = run;
            run += c;
        }
    }
    __syncthreads();
    for (int i = pbeg + t; i < pend; i += 256) {
        unsigned p = pairs[i];
        int dl = (int)(p >> srcbits);
        int pos = atomicAdd(&lcnt[dl], 1);
        csr[pos] = (int)(p & smask);
    }
}

// ========== GAT aggregation v9f (layer 1, FUSED fold epilogue) ==========
#define AGG_CAP 64
#define AGG_PAD 66

__global__ __launch_bounds__(256) void gat_aggregate9f(
    const int* __restrict__ off0, const int* __restrict__ csr0,
    const __half* __restrict__ hs0, const float* __restrict__ als0,
    const float* __restrict__ ald0, const float* __restrict__ bias0,
    const float4* __restrict__ fold0, float* __restrict__ als2_0,
    float* __restrict__ ald2_0, float2* __restrict__ q2_0, int n0,
    const int* __restrict__ off1, const int* __restrict__ csr1,
    const __half* __restrict__ hs1, const float* __restrict__ als1,
    const float* __restrict__ ald1, const float* __restrict__ bias1,
    const float4* __restrict__ fold1, float* __restrict__ als2_1,
    float* __restrict__ ald2_1, float2* __restrict__ q2_1, int n1,
    int nb0) {
    __shared__ uint2 wP[16][AGG_PAD];
    int t = threadIdx.x;
    int slot = t >> 4;
    int sub = t & 15;

    const int* off; const int* csr; const __half* hs; const float* als;
    const float* ald; const float* bias; const float4* fold;
    float* als2; float* ald2; float2* q2; int nd; int b;
    if (blockIdx.x < (unsigned)nb0) {
        b = blockIdx.x;
        off = off0; csr = csr0; hs = hs0; als = als0; ald = ald0; bias = bias0;
        fold = fold0; als2 = als2_0; ald2 = ald2_0; q2 = q2_0; nd = n0;
    } else {
        b = blockIdx.x - nb0;
        off = off1; csr = csr1; hs = hs1; als = als1; ald = ald1; bias = bias1;
        fold = fold1; als2 = als2_1; ald2 = ald2_1; q2 = q2_1; nd = n1;
    }
    int d = b * 16 + slot;
    bool active = d < nd;
    int beg = 0, deg = 0;
    float aldv = 0.f;
    if (active) {
        beg = off[d];
        deg = off[d + 1] - beg;
        aldv = ald[d];
    }
    float4 bl4 = ((const float4*)bias)[sub];
    uint2* WP = wP[slot];

    float sum = 0.f;
    for (int i = sub; i < deg; i += 16) {
        int s = csr[beg + i];
        float a = als[s] + aldv;
        a = (a >= 0.f) ? a : 0.2f * a;
        float w = exp_am8(a);
        sum += w;
        if (i < AGG_CAP) {
            __half hw = __float2half_rn(w);
            __half2 h2 = __half2half2(hw);
            WP[i] = make_uint2(*(const unsigned int*)&h2, (unsigned int)s);
        }
    }
    sum += __shfl_xor(sum, 1);
    sum += __shfl_xor(sum, 2);
    sum += __shfl_xor(sum, 4);
    sum += __shfl_xor(sum, 8);
    float inv = 1.f / fmaxf(sum, 1e-16f);

    int dc = deg < AGG_CAP ? deg : AGG_CAP;
    const uint2* hs4 = (const uint2*)hs;
    __half2 z = __floats2half2_rn(0.f, 0.f);
    __half2 aA = z, aB = z, aC = z, aD = z;
    int i = 0;
    for (; i + 8 <= dc; i += 8) {
        uint4 q0 = *(const uint4*)&WP[i];
        uint4 q1 = *(const uint4*)&WP[i + 2];
        uint4 q2r = *(const uint4*)&WP[i + 4];
        uint4 q3 = *(const uint4*)&WP[i + 6];
        uint2 v0 = hs4[(size_t)q0.y * 16 + sub];
        uint2 v1 = hs4[(size_t)q0.w * 16 + sub];
        uint2 v2 = hs4[(size_t)q1.y * 16 + sub];
        uint2 v3 = hs4[(size_t)q1.w * 16 + sub];
        uint2 v4 = hs4[(size_t)q2r.y * 16 + sub];
        uint2 v5 = hs4[(size_t)q2r.w * 16 + sub];
        uint2 v6 = hs4[(size_t)q3.y * 16 + sub];
        uint2 v7 = hs4[(size_t)q3.w * 16 + sub];
        aA = __hfma2(*(const __half2*)&q0.x, *(const __half2*)&v0.x, aA);
        aB = __hfma2(*(const __half2*)&q0.x, *(const __half2*)&v0.y, aB);
        aC = __hfma2(*(const __half2*)&q0.z, *(const __half2*)&v1.x, aC);
        aD = __hfma2(*(const __half2*)&q0.z, *(const __half2*)&v1.y, aD);
        aA = __hfma2(*(const __half2*)&q1.x, *(const __half2*)&v2.x, aA);
        aB = __hfma2(*(const __half2*)&q1.x, *(const __half2*)&v2.y, aB);
        aC = __hfma2(*(const __half2*)&q1.z, *(const __half2*)&v3.x, aC);
        aD = __hfma2(*(const __half2*)&q1.z, *(const __half2*)&v3.y, aD);
        aA = __hfma2(*(const __half2*)&q2r.x, *(const __half2*)&v4.x, aA);
        aB = __hfma2(*(const __half2*)&q2r.x, *(const __half2*)&v4.y, aB);
        aC = __hfma2(*(const __half2*)&q2r.z, *(const __half2*)&v5.x, aC);
        aD = __hfma2(*(const __half2*)&q2r.z, *(const __half2*)&v5.y, aD);
        aA = __hfma2(*(const __half2*)&q3.x, *(const __half2*)&v6.x, aA);
        aB = __hfma2(*(const __half2*)&q3.x, *(const __half2*)&v6.y, aB);
        aC = __hfma2(*(const __half2*)&q3.z, *(const __half2*)&v7.x, aC);
        aD = __hfma2(*(const __half2*)&q3.z, *(const __half2*)&v7.y, aD);
    }
    for (; i + 2 <= dc; i += 2) {
        uint4 q = *(const uint4*)&WP[i];
        uint2 v0 = hs4[(size_t)q.y * 16 + sub];
        uint2 v1 = hs4[(size_t)q.w * 16 + sub];
        aA = __hfma2(*(const __half2*)&q.x, *(const __half2*)&v0.x, aA);
        aB = __hfma2(*(const __half2*)&q.x, *(const __half2*)&v0.y, aB);
        aC = __hfma2(*(const __half2*)&q.z, *(const __half2*)&v1.x, aC);
        aD = __hfma2(*(const __half2*)&q.z, *(const __half2*)&v1.y, aD);
    }
    if (i < dc) {
        uint2 u = WP[i];
        uint2 v = hs4[(size_t)u.y * 16 + sub];
        aA = __hfma2(*(const __half2*)&u.x, *(const __half2*)&v.x, aA);
        aB = __hfma2(*(const __half2*)&u.x, *(const __half2*)&v.y, aB);
    }
    for (int j = AGG_CAP; j < deg; ++j) {
        int s = csr[beg + j];
        float a = als[s] + aldv;
        a = (a >= 0.f) ? a : 0.2f * a;
        __half hw = __float2half_rn(exp_am8(a));
        __half2 w2 = __half2half2(hw);
        uint2 v = hs4[(size_t)s * 16 + sub];
        aA = __hfma2(w2, *(const __half2*)&v.x, aA);
        aB = __hfma2(w2, *(const __half2*)&v.y, aB);
    }
    float2 fA = __half22float2(aA);
    float2 fB = __half22float2(aB);
    float2 fC = __half22float2(aC);
    float2 fD = __half22float2(aD);
    float o0 = (fA.x + fC.x) * inv + bl4.x;
    float o1 = (fA.y + fC.y) * inv + bl4.y;
    float o2 = (fB.x + fD.x) * inv + bl4.z;
    float o3 = (fB.y + fD.y) * inv + bl4.w;
    if (deg == 0) { o0 = bl4.x; o1 = bl4.y; o2 = bl4.z; o3 = bl4.w; }
    o0 = fmaxf(o0, 0.f); o1 = fmaxf(o1, 0.f);
    o2 = fmaxf(o2, 0.f); o3 = fmaxf(o3, 0.f);

    float4 f0 = fold[4 * sub + 0];
    float4 f1 = fold[4 * sub + 1];
    float4 f2 = fold[4 * sub + 2];
    float4 f3 = fold[4 * sub + 3];
    float a0 = o0 * f0.x + o1 * f1.x + o2 * f2.x + o3 * f3.x;
    float a1 = o0 * f0.y + o1 * f1.y + o2 * f2.y + o3 * f3.y;
    float a2 = o0 * f0.z + o1 * f1.z + o2 * f2.z + o3 * f3.z;
    float a3 = o0 * f0.w + o1 * f1.w + o2 * f2.w + o3 * f3.w;
#pragma unroll
    for (int o = 1; o < 16; o <<= 1) {
        a0 += __shfl_xor(a0, o);
        a1 += __shfl_xor(a1, o);
        a2 += __shfl_xor(a2, o);
        a3 += __shfl_xor(a3, o);
    }
    if (active && sub == 0) {
        als2[d] = a0;
        ald2[d] = a1;
        q2[d] = make_float2(a2, a3);
    }
}

// ========== GAT aggregation v10 (layer 2): one dst per LANE, q-table gathers ==========
__global__ __launch_bounds__(256) void gat_aggregate10p(
    const int* __restrict__ off0, const int* __restrict__ csr0,
    const float2* __restrict__ q0, const float* __restrict__ als0,
    const float* __restrict__ ald0, const float2* __restrict__ bqp,
    float2* __restrict__ out0, int n0,
    const int* __restrict__ off1, const int* __restrict__ csr1,
    const float2* __restrict__ q1, const float* __restrict__ als1,
    const float* __restrict__ ald1,
    float2* __restrict__ out1, int n1,
    int nb0) {
    const int* off; const int* csr; const float2* qt; const float* als;
    const float* ald; float2 bq; float2* outp; int nd; int b;
    if (blockIdx.x < (unsigned)nb0) {
        b = blockIdx.x;
        off = off0; csr = csr0; qt = q0; als = als0; ald = ald0; bq = bqp[1];
        outp = out0; nd = n0;
    } else {
        b = blockIdx.x - nb0;
        off = off1; csr = csr1; qt = q1; als = als1; ald = ald1; bq = bqp[0];
        outp = out1; nd = n1;
    }
    int d = b * 256 + threadIdx.x;
    if (d >= nd) return;
    int beg = off[d], end = off[d + 1];
    float aldv = ald[d];
    float sum = 0.f, ax = 0.f, ay = 0.f;
    int i = beg;
    for (; i + 2 <= end; i += 2) {
        int s0 = csr[i], s1 = csr[i + 1];
        float a0 = als[s0] + aldv;
        float a1 = als[s1] + aldv;
        float2 v0 = qt[s0];
        float2 v1 = qt[s1];
        a0 = (a0 >= 0.f) ? a0 : 0.2f * a0;
        a1 = (a1 >= 0.f) ? a1 : 0.2f * a1;
        float w0 = exp_am8(a0);
        float w1 = exp_am8(a1);
        sum += w0 + w1;
        ax = fmaf(w0, v0.x, ax); ay = fmaf(w0, v0.y, ay);
        ax = fmaf(w1, v1.x, ax); ay = fmaf(w1, v1.y, ay);
    }
    if (i < end) {
        int s = csr[i];
        float a = als[s] + aldv;
        a = (a >= 0.f) ? a : 0.2f * a;
        float w = exp_am8(a);
        float2 v = qt[s];
        sum += w;
        ax = fmaf(w, v.x, ax); ay = fmaf(w, v.y, ay);
    }
    float inv = 1.f / fmaxf(sum, 1e-16f);
    outp[d] = make_float2(ax * inv + bq.x, ay * inv + bq.y);
}

// ---------------- decoder v4: out[e] = pm[row] + pc[col] + bc ----------------
__global__ __launch_bounds__(256) void decoder4_kernel(const int* __restrict__ row,
                                                       const int* __restrict__ col,
                                                       const float2* __restrict__ pm,
                                                       const float2* __restrict__ pc,
                                                       const float* __restrict__ bc,
                                                       float* __restrict__ out, int EL) {
    int e = blockIdx.x * 256 + threadIdx.x;
    if (e >= EL) return;
    float2 a = pm[row[e]];
    float2 b = pc[col[e]];
    *(float2*)(out + 2 * (size_t)e) = make_float2(a.x + b.x + bc[0], a.y + b.y + bc[1]);
}

// ---------------- launch ----------------
extern "C" void kernel_launch(void* const* d_in, const int* in_sizes, int n_in,
                              void* d_out, int out_size, void* d_ws, size_t ws_size,
                              hipStream_t stream) {
    const int D = 128;
    const float* x_m    = (const float*)d_in[0];
    const float* x_c    = (const float*)d_in[1];
    const int*   src_mc = (const int*)d_in[2];
    const int*   dst_mc = (const int*)d_in[3];
    const int*   src_cm = (const int*)d_in[4];
    const int*   dst_cm = (const int*)d_in[5];
    const int*   rowi   = (const int*)d_in[6];
    const int*   coli   = (const int*)d_in[7];
    const float* W1s_mc = (const float*)d_in[8];
    const float* W1d_mc = (const float*)d_in[9];
    const float* a1s_mc = (const float*)d_in[10];
    const float* a1d_mc = (const float*)d_in[11];
    const float* b1_mc  = (const float*)d_in[12];
    const float* W1s_cm = (const float*)d_in[13];
    const float* W1d_cm = (const float*)d_in[14];
    const float* a1s_cm = (const float*)d_in[15];
    const float* a1d_cm = (const float*)d_in[16];
    const float* b1_cm  = (const float*)d_in[17];
    const float* W2s_mc = (const float*)d_in[18];
    const float* W2d_mc = (const float*)d_in[19];
    const float* a2s_mc = (const float*)d_in[20];
    const float* a2d_mc = (const float*)d_in[21];
    const float* b2_mc  = (const float*)d_in[22];
    const float* W2s_cm = (const float*)d_in[23];
    const float* W2d_cm = (const float*)d_in[24];
    const float* a2s_cm = (const float*)d_in[25];
    const float* a2d_cm = (const float*)d_in[26];
    const float* b2_cm  = (const float*)d_in[27];
    const float* Wd1    = (const float*)d_in[28];
    const float* bd1    = (const float*)d_in[29];
    const float* Wd2    = (const float*)d_in[30];
    const float* bd2    = (const float*)d_in[31];

    const int N_M = in_sizes[0] / D;
    const int N_C = in_sizes[1] / D;
    const int E   = in_sizes[2];
    const int EL  = in_sizes[6];
    float* out = (float*)d_out;

    uint8_t* base = (uint8_t*)d_ws;
    size_t off = 0;
    auto carve = [&](size_t bytes) -> void* {
        void* p = base + off;
        off += (bytes + 255) & ~(size_t)255;
        return p;
    };
    __half* hsA_h = (__half*)carve((size_t)N_M * 64 * 2);
    __half* hsB_h = (__half*)carve((size_t)N_C * 64 * 2);
    float2* qA    = (float2*)carve((size_t)N_M * 8);
    float2* qB    = (float2*)carve((size_t)N_C * 8);
    float2* pm_m  = (float2*)carve((size_t)N_M * 8);
    float2* pm_c  = (float2*)carve((size_t)N_C * 8);
    float* als_mc = (float*)carve((size_t)N_M * 4);
    float* ald_cm = (float*)carve((size_t)N_M * 4);
    float* als_cm = (float*)carve((size_t)N_C * 4);
    float* ald_mc = (float*)carve((size_t)N_C * 4);
    float* als2_mc = (float*)carve((size_t)N_M * 4);
    float* ald2_cm = (float*)carve((size_t)N_M * 4);
    float* als2_cm = (float*)carve((size_t)N_C * 4);
    float* ald2_mc = (float*)carve((size_t)N_C * 4);
    int* off_mc = (int*)carve((size_t)(N_C + 1) * 4);
    int* off_cm = (int*)carve((size_t)(N_M + 1) * 4);
    int* csr_mc = (int*)carve((size_t)E * 4);
    int* csr_cm = (int*)carve((size_t)E * 4);
    unsigned* pairs_mc = (unsigned*)carve((size_t)E * 4);
    unsigned* pairs_cm = (unsigned*)carve((size_t)E * 4);
    int* bcnt_base = (int*)carve(512 * 4);
    int* bcnt_mc = bcnt_base;
    int* bcnt_cm = bcnt_base + 256;
    int* bbase_mc = (int*)carve(257 * 4);
    int* bbase_cm = (int*)carve(257 * 4);
    int* bcur_mc = (int*)carve(256 * 4);
    int* bcur_cm = (int*)carve(256 * 4);
    _Float16* wp1A = (_Float16*)carve(128 * 128 * 2);
    _Float16* wp1B = (_Float16*)carve(128 * 128 * 2);
    float* Wc = (float*)carve(256 * 4);
    float* bc = (float*)carve(256);
    float* bq = (float*)carve(256);
    float2* bq2 = (float2*)bq;
    float4* foldA = (float4*)carve(64 * 16);
    float4* foldB = (float4*)carve(64 * 16);

    int shA = 0; while (((N_C + (1 << shA) - 1) >> shA) > 256) shA++;
    int shB = 0; while (((N_M + (1 << shB) - 1) >> shB) > 256) shB++;
    int nbkA = (N_C + (1 << shA) - 1) >> shA;
    int nbkB = (N_M + (1 << shB) - 1) >> shB;
    int maxN = N_M > N_C ? N_M : N_C;
    int srcbits = 1; while ((1 << srcbits) < maxN) srcbits++;

    // ---- L1: pack_w2 + decoder_prep3 + bcnt zeroing, fused ----
    prep_all<<<130, 256, 0, stream>>>(W1s_mc, W1d_cm, wp1A, W1s_cm, W1d_mc, wp1B,
                                      Wd1, bd1, Wd2, bd2, b2_cm, b2_mc,
                                      W2s_mc, a2s_mc, W2d_cm, a2d_cm,
                                      W2s_cm, a2s_cm, W2d_mc, a2d_mc,
                                      Wc, bc, bq, foldA, foldB, bcnt_base);

    // ---- L2: proj_m | proj_c | bucket_hist, fused (512 thr, LDS-staged coalesced X) ----
    int nbm = (N_M + 127) / 128;
    int nbc = (N_C + 127) / 128;
    int nblk = (E + 4095) / 4096;
    size_t smem_bytes = 32768 + (size_t)128 * XPAD * 2;
    fused_proj_hist<<<nbm + nbc + 2 * nblk, 512, smem_bytes, stream>>>(
        x_m, N_M, wp1A, a1s_mc, a1d_cm, hsA_h, als_mc, ald_cm, nbm,
        x_c, N_C, wp1B, a1s_cm, a1d_mc, hsB_h, als_cm, ald_mc, nbc,
        dst_mc, bcnt_mc, shA, dst_cm, bcnt_cm, shB, E, nblk);

    // ---- CSR build tail ----
    bucket_scan<<<1, 128, 0, stream>>>(bcnt_mc, nbkA, bbase_mc, bcur_mc, off_mc, N_C,
                                       bcnt_cm, nbkB, bbase_cm, bcur_cm, off_cm, N_M, E);
    bucket_scatter<<<2 * nblk, 256, 0, stream>>>(
        src_mc, dst_mc, bcur_mc, pairs_mc,
        src_cm, dst_cm, bcur_cm, pairs_cm, E, nblk, shA, shB, srcbits);
    bucket_expand2<<<nbkA + nbkB, 256, 0, stream>>>(
        pairs_mc, bbase_mc, N_C, off_mc, csr_mc, shA, nbkA,
        pairs_cm, bbase_cm, N_M, off_cm, csr_cm, shB, srcbits);

    int nb_c16 = (N_C + 15) / 16;
    int nb_m16 = (N_M + 15) / 16;

    // ---- Layer-1 aggregate fused with layer-2 fold ----
    gat_aggregate9f<<<nb_c16 + nb_m16, 256, 0, stream>>>(
        off_mc, csr_mc, hsA_h, als_mc, ald_mc, b1_mc, foldB, als2_cm, ald2_mc, qB, N_C,
        off_cm, csr_cm, hsB_h, als_cm, ald_cm, b1_cm, foldA, als2_mc, ald2_cm, qA, N_M,
        nb_c16);

    // ---- Layer-2 aggregate (q-table gathers) ----
    int nb_c256 = (N_C + 255) / 256;
    int nb_m256 = (N_M + 255) / 256;
    gat_aggregate10p<<<nb_c256 + nb_m256, 256, 0, stream>>>(
        off_mc, csr_mc, qA, als2_mc, ald2_mc, bq2, pm_c, N_C,
        off_cm, csr_cm, qB, als2_cm, ald2_cm, pm_m, N_M, nb_c256);

    // ---- Decoder ----
    decoder4_kernel<<<(EL + 255) / 256, 256, 0, stream>>>(rowi, coli, pm_m, pm_c, bc, out, EL);
}

// Round 30
// 197.394 us; speedup vs baseline: 1.0072x; 1.0072x over previous
//
#include <hip/hip_runtime.h>
#include <hip/hip_fp16.h>
#include <cstdint>
#include <cstddef>

typedef _Float16 f16x8 __attribute__((ext_vector_type(8)));
typedef float f32x4 __attribute__((ext_vector_type(4)));

__device__ __forceinline__ float exp_am8(float a) {
    return __builtin_amdgcn_exp2f(fmaf(a, 1.442695040888963f, -11.541560327111707f));
}

// ================= prep (fused): pack_w2 (blocks 0..127) + decoder_prep3 (128) + zero (129)
__global__ void prep_all(
    const float* __restrict__ Wa0, const float* __restrict__ Wb0, _Float16* __restrict__ P0,
    const float* __restrict__ Wa1, const float* __restrict__ Wb1, _Float16* __restrict__ P1,
    const float* __restrict__ Wd1, const float* __restrict__ bd1,
    const float* __restrict__ Wd2, const float* __restrict__ bd2,
    const float* __restrict__ b2_cm, const float* __restrict__ b2_mc,
    const float* __restrict__ W2s_mc, const float* __restrict__ a2s_mc,
    const float* __restrict__ W2d_cm, const float* __restrict__ a2d_cm,
    const float* __restrict__ W2s_cm, const float* __restrict__ a2s_cm,
    const float* __restrict__ W2d_mc, const float* __restrict__ a2d_mc,
    float* __restrict__ Wc, float* __restrict__ bc, float* __restrict__ bq,
    float4* __restrict__ foldA, float4* __restrict__ foldB,
    int* __restrict__ bcnt_base) {
    __shared__ float WcS[256];
    int b = blockIdx.x;
    int t = threadIdx.x;
    if (b < 128) {
        const float* Wa; const float* Wb; _Float16* Wp; int lb;
        if (b < 64) { Wa = Wa0; Wb = Wb0; Wp = P0; lb = b; }
        else        { Wa = Wa1; Wb = Wb1; Wp = P1; lb = b - 64; }
        constexpr int K = 128;
        constexpr int NKB = K / 32;
        int i = lb * 256 + t;
        if (i >= 128 * K) return;
        int k = i >> 7, c = i & 127;
        float v = (c < 64) ? Wa[k * 64 + c] : Wb[k * 64 + (c - 64)];
        int ct = c >> 4, lr = c & 15, kb = k >> 5, lk = (k & 31) >> 3, e = k & 7;
        Wp[((ct * NKB + kb) * 64 + (lr + 16 * lk)) * 8 + e] = (_Float16)v;
    } else if (b == 128) {
        int k = t >> 1, c = t & 1;
        float s = 0.f;
        for (int j = 0; j < 64; ++j) s += Wd1[k * 64 + j] * Wd2[j * 2 + c];
        Wc[k * 2 + c] = s;
        WcS[k * 2 + c] = s;
        if (k == 0) {
            float bv = bd2[c];
            for (int j = 0; j < 64; ++j) bv += bd1[j] * Wd2[j * 2 + c];
            bc[c] = bv;
        }
        __syncthreads();
        if (t < 2) {
            float v = 0.f;
            for (int j = 0; j < 64; ++j) v += b2_cm[j] * WcS[j * 2 + t];
            bq[t] = v;
        } else if (t < 4) {
            int cc = t - 2;
            float v = 0.f;
            for (int j = 0; j < 64; ++j) v += b2_mc[j] * WcS[(64 + j) * 2 + cc];
            bq[t] = v;
        }
        if (t < 64) {
            int j = t;
            float fa = 0.f, fd = 0.f, qx = 0.f, qy = 0.f;
            for (int cc = 0; cc < 64; ++cc) {
                float ws = W2s_mc[j * 64 + cc];
                fa += ws * a2s_mc[cc];
                qx += ws * WcS[(64 + cc) * 2 + 0];
                qy += ws * WcS[(64 + cc) * 2 + 1];
                fd += W2d_cm[j * 64 + cc] * a2d_cm[cc];
            }
            foldA[j] = make_float4(fa, fd, qx, qy);
        } else if (t < 128) {
            int j = t - 64;
            float fa = 0.f, fd = 0.f, qx = 0.f, qy = 0.f;
            for (int cc = 0; cc < 64; ++cc) {
                float ws = W2s_cm[j * 64 + cc];
                fa += ws * a2s_cm[cc];
                qx += ws * WcS[cc * 2 + 0];
                qy += ws * WcS[cc * 2 + 1];
                fd += W2d_mc[j * 64 + cc] * a2d_mc[cc];
            }
            foldB[j] = make_float4(fa, fd, qx, qy);
        }
    } else {
        bcnt_base[t] = 0;
        bcnt_base[t + 256] = 0;
    }
}

// ========== proj body v3b (512 thr, 128 rows): col-split waves, W in registers ==========
// Wave wv owns output cols [wv*16, wv*16+16) for ALL 128 rows. Waves 0..3 = hs cols
// (write hs, reduce alpha0); waves 4..7 = hd cols (no hs write, reduce alpha1).
// LDS = X tile 18.4KB + 1KB reduction -> 4 blocks/CU.
#define XPAD 72

__device__ __forceinline__ void proj_body(const float* __restrict__ X, int N,
                                          const _Float16* __restrict__ Wp,
                                          const float* __restrict__ a0v,
                                          const float* __restrict__ a1v,
                                          __half* __restrict__ out0,
                                          float* __restrict__ al0,
                                          float* __restrict__ al1,
                                          char* smem, int blk) {
    constexpr int K = 128;
    _Float16* Xs = (_Float16*)smem;                       // [128][XPAD]
    float* red0 = (float*)(smem + 128 * XPAD * 2);        // [128]
    float* red1 = red0 + 128;                             // [128]
    int t = threadIdx.x;
    int wv = t >> 6, lane = t & 63, lr = lane & 15, lk = lane >> 4;
    int rt = blk * 128;
    int xrow = t >> 4;
    int xcp = t & 15;

    // per-wave W fragments for col tile wv (4 x f16x8 in registers, L2-hot load)
    f16x8 wfr[4];
#pragma unroll
    for (int kbb = 0; kbb < 4; ++kbb)
        wfr[kbb] = ((const f16x8*)Wp)[(wv * 4 + kbb) * 64 + lane];

    if (t < 128) { red0[t] = 0.f; red1[t] = 0.f; }

    f32x4 acc[8];
#pragma unroll
    for (int i = 0; i < 8; ++i) acc[i] = f32x4{0.f, 0.f, 0.f, 0.f};

#pragma unroll
    for (int half = 0; half < 2; ++half) {
        __syncthreads();
#pragma unroll
        for (int pass = 0; pass < 4; ++pass) {
            int r = pass * 32 + xrow;
            int grow = rt + r;
            if (grow >= N) grow = N - 1;
            float4 v = *(const float4*)(X + (size_t)grow * K + half * 64 + xcp * 4);
            __half2 h01 = __floats2half2_rn(v.x, v.y);
            __half2 h23 = __floats2half2_rn(v.z, v.w);
            uint2 pk;
            pk.x = *(const unsigned int*)&h01;
            pk.y = *(const unsigned int*)&h23;
            *(uint2*)&Xs[r * XPAD + xcp * 4] = pk;
        }
        __syncthreads();
#pragma unroll
        for (int rt8 = 0; rt8 < 8; ++rt8) {
#pragma unroll
            for (int kb = 0; kb < 2; ++kb) {
                f16x8 bf = *(const f16x8*)&Xs[(rt8 * 16 + lr) * XPAD + kb * 32 + lk * 8];
                acc[rt8] = __builtin_amdgcn_mfma_f32_16x16x32_f16(
                    wfr[half * 2 + kb], bf, acc[rt8], 0, 0, 0);
            }
        }
    }

    // role-split epilogue: wv<4 -> hs cols (alpha0, hs write); wv>=4 -> hd cols (alpha1)
    bool is_s = wv < 4;
    float4 aq = is_s ? ((const float4*)a0v)[wv * 4 + lk]
                     : ((const float4*)a1v)[(wv - 4) * 4 + lk];
    float* red = is_s ? red0 : red1;
#pragma unroll
    for (int rt8 = 0; rt8 < 8; ++rt8) {
        f32x4 v = acc[rt8];
        float p = v[0] * aq.x + v[1] * aq.y + v[2] * aq.z + v[3] * aq.w;
        p += __shfl_xor(p, 16); p += __shfl_xor(p, 32);
        if (lane < 16) atomicAdd(&red[rt8 * 16 + lr], p);
        int row = rt + rt8 * 16 + lr;
        if (is_s && row < N) {
            __half2 h01 = __floats2half2_rn(v[0], v[1]);
            __half2 h23 = __floats2half2_rn(v[2], v[3]);
            uint2 pk;
            pk.x = *(const unsigned int*)&h01;
            pk.y = *(const unsigned int*)&h23;
            *(uint2*)(out0 + ((size_t)row << 6) + wv * 16 + lk * 4) = pk;
        }
    }
    __syncthreads();
    if (t < 128) {
        int row = rt + t;
        if (row < N) { al0[row] = red0[t]; al1[row] = red1[t]; }
    }
}

// ========== fused launch (512 thr): proj_m | proj_c | bucket_hist ==========
__global__ __launch_bounds__(512) void fused_proj_hist(
    const float* __restrict__ Xm, int Nm, const _Float16* __restrict__ WpA,
    const float* __restrict__ a0A, const float* __restrict__ a1A,
    __half* __restrict__ outA, float* __restrict__ al0A, float* __restrict__ al1A, int nbm,
    const float* __restrict__ Xc, int Nc, const _Float16* __restrict__ WpB,
    const float* __restrict__ a0B, const float* __restrict__ a1B,
    __half* __restrict__ outB, float* __restrict__ al0B, float* __restrict__ al1B, int nbc,
    const int* __restrict__ dmc, int* __restrict__ bcnt_mc, int shA,
    const int* __restrict__ dcm, int* __restrict__ bcnt_cm, int shB, int E, int nblk) {
    extern __shared__ __align__(16) char smem[];
    int b = blockIdx.x;
    if (b < nbm) {
        proj_body(Xm, Nm, WpA, a0A, a1A, outA, al0A, al1A, smem, b);
        return;
    }
    b -= nbm;
    if (b < nbc) {
        proj_body(Xc, Nc, WpB, a0B, a1B, outB, al0B, al1B, smem, b);
        return;
    }
    b -= nbc;
    int* h = (int*)smem;
    const int* dst; int* bcnt; int sh; int base;
    if (b < nblk) { dst = dmc; bcnt = bcnt_mc; sh = shA; base = b * 4096; }
    else { dst = dcm; bcnt = bcnt_cm; sh = shB; base = (b - nblk) * 4096; }
    int t = threadIdx.x;
    if (t < 256) h[t] = 0;
    __syncthreads();
#pragma unroll
    for (int j = 0; j < 8; ++j) {
        int i = base + j * 512 + t;
        if (i < E) atomicAdd(&h[dst[i] >> sh], 1);
    }
    __syncthreads();
    if (t < 256) {
        int c = h[t];
        if (c > 0) atomicAdd(&bcnt[t], c);
    }
}

// ================= CSR build tail =================
__global__ void bucket_scan(const int* __restrict__ bcntA, int nbkA,
                            int* __restrict__ bbaseA, int* __restrict__ bcurA,
                            int* __restrict__ offA, int nA,
                            const int* __restrict__ bcntB, int nbkB,
                            int* __restrict__ bbaseB, int* __restrict__ bcurB,
                            int* __restrict__ offB, int nB, int E) {
    int t = threadIdx.x;
    if (t == 0) {
        int run = 0;
        for (int i = 0; i < nbkA; ++i) { bbaseA[i] = run; bcurA[i] = run; run += bcntA[i]; }
        bbaseA[nbkA] = run;
        offA[nA] = E;
    }
    if (t == 64) {
        int run = 0;
        for (int i = 0; i < nbkB; ++i) { bbaseB[i] = run; bcurB[i] = run; run += bcntB[i]; }
        bbaseB[nbkB] = run;
        offB[nB] = E;
    }
}

__global__ __launch_bounds__(256) void bucket_scatter(
    const int* __restrict__ srcA, const int* __restrict__ dstA,
    int* __restrict__ bcurA, unsigned* __restrict__ pairsA,
    const int* __restrict__ srcB, const int* __restrict__ dstB,
    int* __restrict__ bcurB, unsigned* __restrict__ pairsB,
    int E, int nblkA, int shA, int shB, int srcbits) {
    __shared__ int bcnt[256];
    __shared__ int bbase[256];
    const int* src; const int* dst; int* bcur; unsigned* pairs; int sh; int base;
    if ((int)blockIdx.x < nblkA) {
        src = srcA; dst = dstA; bcur = bcurA; pairs = pairsA; sh = shA;
        base = blockIdx.x * 4096;
    } else {
        src = srcB; dst = dstB; bcur = bcurB; pairs = pairsB; sh = shB;
        base = (blockIdx.x - nblkA) * 4096;
    }
    int t = threadIdx.x;
    int msk = (1 << sh) - 1;
    bcnt[t] = 0;
    __syncthreads();
    int sreg[16], dreg[16];
#pragma unroll
    for (int j = 0; j < 16; ++j) {
        int i = base + j * 256 + t;
        if (i < E) {
            sreg[j] = src[i];
            dreg[j] = dst[i];
            atomicAdd(&bcnt[dreg[j] >> sh], 1);
        } else {
            dreg[j] = -1;
        }
    }
    __syncthreads();
    {
        int c = bcnt[t];
        int g = (c > 0) ? atomicAdd(&bcur[t], c) : 0;
        bbase[t] = g;
        bcnt[t] = 0;
    }
    __syncthreads();
#pragma unroll
    for (int j = 0; j < 16; ++j) {
        if (dreg[j] >= 0) {
            int b = dreg[j] >> sh;
            int r = atomicAdd(&bcnt[b], 1);
            pairs[bbase[b] + r] = ((unsigned)(dreg[j] & msk) << srcbits) | (unsigned)sreg[j];
        }
    }
}

__global__ __launch_bounds__(256) void bucket_expand2(
    const unsigned* __restrict__ pairsA, const int* __restrict__ bbaseA, int nA,
    int* __restrict__ offA, int* __restrict__ csrA, int shA, int nbA,
    const unsigned* __restrict__ pairsB, const int* __restrict__ bbaseB, int nB,
    int* __restrict__ offB, int* __restrict__ csrB, int shB, int srcbits) {
    __shared__ int lcnt[1024];
    __shared__ int red[256];
    const unsigned* pairs; const int* bbase; int n; int* off; int* csr; int sh; int b;
    if ((int)blockIdx.x < nbA) {
        pairs = pairsA; bbase = bbaseA; n = nA; off = offA; csr = csrA; sh = shA;
        b = blockIdx.x;
    } else {
        pairs = pairsB; bbase = bbaseB; n = nB; off = offB; csr = csrB; sh = shB;
        b = blockIdx.x - nbA;
    }
    int dpb = 1 << sh;
    int d0 = b << sh;
    int t = threadIdx.x;
    unsigned smask = (1u << srcbits) - 1u;
    for (int dl = t; dl < dpb; dl += 256) lcnt[dl] = 0;
    __syncthreads();
    int pbeg = bbase[b], pend = bbase[b + 1];
    for (int i = pbeg + t; i < pend; i += 256)
        atomicAdd(&lcnt[pairs[i] >> srcbits], 1);
    __syncthreads();
    int per = (dpb + 255) >> 8;
    int i0 = t * per;
    int s = 0;
    for (int j = 0; j < per; ++j) {
        int dl = i0 + j;
        if (dl < dpb) s += lcnt[dl];
    }
    red[t] = s;
    __syncthreads();
    for (int st = 1; st < 256; st <<= 1) {
        int tmp = (t >= st) ? red[t - st] : 0;
        __syncthreads();
        red[t] += tmp;
        __syncthreads();
    }
    int run = pbeg + red[t] - s;
    for (int j = 0; j < per; ++j) {
        int dl = i0 + j;
        if (dl < dpb) {
            int c = lcnt[dl];
            if (d0 + dl < n) off[d0 + dl] = run;
            lcnt[dl] = run;
            run += c;
        }
    }
    __syncthreads();
    for (int i = pbeg + t; i < pend; i += 256) {
        unsigned p = pairs[i];
        int dl = (int)(p >> srcbits);
        int pos = atomicAdd(&lcnt[dl], 1);
        csr[pos] = (int)(p & smask);
    }
}

// ========== GAT aggregation v9f (layer 1, FUSED fold epilogue) ==========
#define AGG_CAP 64
#define AGG_PAD 66

__global__ __launch_bounds__(256) void gat_aggregate9f(
    const int* __restrict__ off0, const int* __restrict__ csr0,
    const __half* __restrict__ hs0, const float* __restrict__ als0,
    const float* __restrict__ ald0, const float* __restrict__ bias0,
    const float4* __restrict__ fold0, float* __restrict__ als2_0,
    float* __restrict__ ald2_0, float2* __restrict__ q2_0, int n0,
    const int* __restrict__ off1, const int* __restrict__ csr1,
    const __half* __restrict__ hs1, const float* __restrict__ als1,
    const float* __restrict__ ald1, const float* __restrict__ bias1,
    const float4* __restrict__ fold1, float* __restrict__ als2_1,
    float* __restrict__ ald2_1, float2* __restrict__ q2_1, int n1,
    int nb0) {
    __shared__ uint2 wP[16][AGG_PAD];
    int t = threadIdx.x;
    int slot = t >> 4;
    int sub = t & 15;

    const int* off; const int* csr; const __half* hs; const float* als;
    const float* ald; const float* bias; const float4* fold;
    float* als2; float* ald2; float2* q2; int nd; int b;
    if (blockIdx.x < (unsigned)nb0) {
        b = blockIdx.x;
        off = off0; csr = csr0; hs = hs0; als = als0; ald = ald0; bias = bias0;
        fold = fold0; als2 = als2_0; ald2 = ald2_0; q2 = q2_0; nd = n0;
    } else {
        b = blockIdx.x - nb0;
        off = off1; csr = csr1; hs = hs1; als = als1; ald = ald1; bias = bias1;
        fold = fold1; als2 = als2_1; ald2 = ald2_1; q2 = q2_1; nd = n1;
    }
    int d = b * 16 + slot;
    bool active = d < nd;
    int beg = 0, deg = 0;
    float aldv = 0.f;
    if (active) {
        beg = off[d];
        deg = off[d + 1] - beg;
        aldv = ald[d];
    }
    float4 bl4 = ((const float4*)bias)[sub];
    uint2* WP = wP[slot];

    float sum = 0.f;
    for (int i = sub; i < deg; i += 16) {
        int s = csr[beg + i];
        float a = als[s] + aldv;
        a = (a >= 0.f) ? a : 0.2f * a;
        float w = exp_am8(a);
        sum += w;
        if (i < AGG_CAP) {
            __half hw = __float2half_rn(w);
            __half2 h2 = __half2half2(hw);
            WP[i] = make_uint2(*(const unsigned int*)&h2, (unsigned int)s);
        }
    }
    sum += __shfl_xor(sum, 1);
    sum += __shfl_xor(sum, 2);
    sum += __shfl_xor(sum, 4);
    sum += __shfl_xor(sum, 8);
    float inv = 1.f / fmaxf(sum, 1e-16f);

    int dc = deg < AGG_CAP ? deg : AGG_CAP;
    const uint2* hs4 = (const uint2*)hs;
    __half2 z = __floats2half2_rn(0.f, 0.f);
    __half2 aA = z, aB = z, aC = z, aD = z;
    int i = 0;
    for (; i + 8 <= dc; i += 8) {
        uint4 q0 = *(const uint4*)&WP[i];
        uint4 q1 = *(const uint4*)&WP[i + 2];
        uint4 q2r = *(const uint4*)&WP[i + 4];
        uint4 q3 = *(const uint4*)&WP[i + 6];
        uint2 v0 = hs4[(size_t)q0.y * 16 + sub];
        uint2 v1 = hs4[(size_t)q0.w * 16 + sub];
        uint2 v2 = hs4[(size_t)q1.y * 16 + sub];
        uint2 v3 = hs4[(size_t)q1.w * 16 + sub];
        uint2 v4 = hs4[(size_t)q2r.y * 16 + sub];
        uint2 v5 = hs4[(size_t)q2r.w * 16 + sub];
        uint2 v6 = hs4[(size_t)q3.y * 16 + sub];
        uint2 v7 = hs4[(size_t)q3.w * 16 + sub];
        aA = __hfma2(*(const __half2*)&q0.x, *(const __half2*)&v0.x, aA);
        aB = __hfma2(*(const __half2*)&q0.x, *(const __half2*)&v0.y, aB);
        aC = __hfma2(*(const __half2*)&q0.z, *(const __half2*)&v1.x, aC);
        aD = __hfma2(*(const __half2*)&q0.z, *(const __half2*)&v1.y, aD);
        aA = __hfma2(*(const __half2*)&q1.x, *(const __half2*)&v2.x, aA);
        aB = __hfma2(*(const __half2*)&q1.x, *(const __half2*)&v2.y, aB);
        aC = __hfma2(*(const __half2*)&q1.z, *(const __half2*)&v3.x, aC);
        aD = __hfma2(*(const __half2*)&q1.z, *(const __half2*)&v3.y, aD);
        aA = __hfma2(*(const __half2*)&q2r.x, *(const __half2*)&v4.x, aA);
        aB = __hfma2(*(const __half2*)&q2r.x, *(const __half2*)&v4.y, aB);
        aC = __hfma2(*(const __half2*)&q2r.z, *(const __half2*)&v5.x, aC);
        aD = __hfma2(*(const __half2*)&q2r.z, *(const __half2*)&v5.y, aD);
        aA = __hfma2(*(const __half2*)&q3.x, *(const __half2*)&v6.x, aA);
        aB = __hfma2(*(const __half2*)&q3.x, *(const __half2*)&v6.y, aB);
        aC = __hfma2(*(const __half2*)&q3.z, *(const __half2*)&v7.x, aC);
        aD = __hfma2(*(const __half2*)&q3.z, *(const __half2*)&v7.y, aD);
    }
    for (; i + 2 <= dc; i += 2) {
        uint4 q = *(const uint4*)&WP[i];
        uint2 v0 = hs4[(size_t)q.y * 16 + sub];
        uint2 v1 = hs4[(size_t)q.w * 16 + sub];
        aA = __hfma2(*(const __half2*)&q.x, *(const __half2*)&v0.x, aA);
        aB = __hfma2(*(const __half2*)&q.x, *(const __half2*)&v0.y, aB);
        aC = __hfma2(*(const __half2*)&q.z, *(const __half2*)&v1.x, aC);
        aD = __hfma2(*(const __half2*)&q.z, *(const __half2*)&v1.y, aD);
    }
    if (i < dc) {
        uint2 u = WP[i];
        uint2 v = hs4[(size_t)u.y * 16 + sub];
        aA = __hfma2(*(const __half2*)&u.x, *(const __half2*)&v.x, aA);
        aB = __hfma2(*(const __half2*)&u.x, *(const __half2*)&v.y, aB);
    }
    for (int j = AGG_CAP; j < deg; ++j) {
        int s = csr[beg + j];
        float a = als[s] + aldv;
        a = (a >= 0.f) ? a : 0.2f * a;
        __half hw = __float2half_rn(exp_am8(a));
        __half2 w2 = __half2half2(hw);
        uint2 v = hs4[(size_t)s * 16 + sub];
        aA = __hfma2(w2, *(const __half2*)&v.x, aA);
        aB = __hfma2(w2, *(const __half2*)&v.y, aB);
    }
    float2 fA = __half22float2(aA);
    float2 fB = __half22float2(aB);
    float2 fC = __half22float2(aC);
    float2 fD = __half22float2(aD);
    float o0 = (fA.x + fC.x) * inv + bl4.x;
    float o1 = (fA.y + fC.y) * inv + bl4.y;
    float o2 = (fB.x + fD.x) * inv + bl4.z;
    float o3 = (fB.y + fD.y) * inv + bl4.w;
    if (deg == 0) { o0 = bl4.x; o1 = bl4.y; o2 = bl4.z; o3 = bl4.w; }
    o0 = fmaxf(o0, 0.f); o1 = fmaxf(o1, 0.f);
    o2 = fmaxf(o2, 0.f); o3 = fmaxf(o3, 0.f);

    float4 f0 = fold[4 * sub + 0];
    float4 f1 = fold[4 * sub + 1];
    float4 f2 = fold[4 * sub + 2];
    float4 f3 = fold[4 * sub + 3];
    float a0 = o0 * f0.x + o1 * f1.x + o2 * f2.x + o3 * f3.x;
    float a1 = o0 * f0.y + o1 * f1.y + o2 * f2.y + o3 * f3.y;
    float a2 = o0 * f0.z + o1 * f1.z + o2 * f2.z + o3 * f3.z;
    float a3 = o0 * f0.w + o1 * f1.w + o2 * f2.w + o3 * f3.w;
#pragma unroll
    for (int o = 1; o < 16; o <<= 1) {
        a0 += __shfl_xor(a0, o);
        a1 += __shfl_xor(a1, o);
        a2 += __shfl_xor(a2, o);
        a3 += __shfl_xor(a3, o);
    }
    if (active && sub == 0) {
        als2[d] = a0;
        ald2[d] = a1;
        q2[d] = make_float2(a2, a3);
    }
}

// ========== GAT aggregation v10 (layer 2): one dst per LANE, q-table gathers ==========
__global__ __launch_bounds__(256) void gat_aggregate10p(
    const int* __restrict__ off0, const int* __restrict__ csr0,
    const float2* __restrict__ q0, const float* __restrict__ als0,
    const float* __restrict__ ald0, const float2* __restrict__ bqp,
    float2* __restrict__ out0, int n0,
    const int* __restrict__ off1, const int* __restrict__ csr1,
    const float2* __restrict__ q1, const float* __restrict__ als1,
    const float* __restrict__ ald1,
    float2* __restrict__ out1, int n1,
    int nb0) {
    const int* off; const int* csr; const float2* qt; const float* als;
    const float* ald; float2 bq; float2* outp; int nd; int b;
    if (blockIdx.x < (unsigned)nb0) {
        b = blockIdx.x;
        off = off0; csr = csr0; qt = q0; als = als0; ald = ald0; bq = bqp[1];
        outp = out0; nd = n0;
    } else {
        b = blockIdx.x - nb0;
        off = off1; csr = csr1; qt = q1; als = als1; ald = ald1; bq = bqp[0];
        outp = out1; nd = n1;
    }
    int d = b * 256 + threadIdx.x;
    if (d >= nd) return;
    int beg = off[d], end = off[d + 1];
    float aldv = ald[d];
    float sum = 0.f, ax = 0.f, ay = 0.f;
    int i = beg;
    for (; i + 2 <= end; i += 2) {
        int s0 = csr[i], s1 = csr[i + 1];
        float a0 = als[s0] + aldv;
        float a1 = als[s1] + aldv;
        float2 v0 = qt[s0];
        float2 v1 = qt[s1];
        a0 = (a0 >= 0.f) ? a0 : 0.2f * a0;
        a1 = (a1 >= 0.f) ? a1 : 0.2f * a1;
        float w0 = exp_am8(a0);
        float w1 = exp_am8(a1);
        sum += w0 + w1;
        ax = fmaf(w0, v0.x, ax); ay = fmaf(w0, v0.y, ay);
        ax = fmaf(w1, v1.x, ax); ay = fmaf(w1, v1.y, ay);
    }
    if (i < end) {
        int s = csr[i];
        float a = als[s] + aldv;
        a = (a >= 0.f) ? a : 0.2f * a;
        float w = exp_am8(a);
        float2 v = qt[s];
        sum += w;
        ax = fmaf(w, v.x, ax); ay = fmaf(w, v.y, ay);
    }
    float inv = 1.f / fmaxf(sum, 1e-16f);
    outp[d] = make_float2(ax * inv + bq.x, ay * inv + bq.y);
}

// ---------------- decoder v4: out[e] = pm[row] + pc[col] + bc ----------------
__global__ __launch_bounds__(256) void decoder4_kernel(const int* __restrict__ row,
                                                       const int* __restrict__ col,
                                                       const float2* __restrict__ pm,
                                                       const float2* __restrict__ pc,
                                                       const float* __restrict__ bc,
                                                       float* __restrict__ out, int EL) {
    int e = blockIdx.x * 256 + threadIdx.x;
    if (e >= EL) return;
    float2 a = pm[row[e]];
    float2 b = pc[col[e]];
    *(float2*)(out + 2 * (size_t)e) = make_float2(a.x + b.x + bc[0], a.y + b.y + bc[1]);
}

// ---------------- launch ----------------
extern "C" void kernel_launch(void* const* d_in, const int* in_sizes, int n_in,
                              void* d_out, int out_size, void* d_ws, size_t ws_size,
                              hipStream_t stream) {
    const int D = 128;
    const float* x_m    = (const float*)d_in[0];
    const float* x_c    = (const float*)d_in[1];
    const int*   src_mc = (const int*)d_in[2];
    const int*   dst_mc = (const int*)d_in[3];
    const int*   src_cm = (const int*)d_in[4];
    const int*   dst_cm = (const int*)d_in[5];
    const int*   rowi   = (const int*)d_in[6];
    const int*   coli   = (const int*)d_in[7];
    const float* W1s_mc = (const float*)d_in[8];
    const float* W1d_mc = (const float*)d_in[9];
    const float* a1s_mc = (const float*)d_in[10];
    const float* a1d_mc = (const float*)d_in[11];
    const float* b1_mc  = (const float*)d_in[12];
    const float* W1s_cm = (const float*)d_in[13];
    const float* W1d_cm = (const float*)d_in[14];
    const float* a1s_cm = (const float*)d_in[15];
    const float* a1d_cm = (const float*)d_in[16];
    const float* b1_cm  = (const float*)d_in[17];
    const float* W2s_mc = (const float*)d_in[18];
    const float* W2d_mc = (const float*)d_in[19];
    const float* a2s_mc = (const float*)d_in[20];
    const float* a2d_mc = (const float*)d_in[21];
    const float* b2_mc  = (const float*)d_in[22];
    const float* W2s_cm = (const float*)d_in[23];
    const float* W2d_cm = (const float*)d_in[24];
    const float* a2s_cm = (const float*)d_in[25];
    const float* a2d_cm = (const float*)d_in[26];
    const float* b2_cm  = (const float*)d_in[27];
    const float* Wd1    = (const float*)d_in[28];
    const float* bd1    = (const float*)d_in[29];
    const float* Wd2    = (const float*)d_in[30];
    const float* bd2    = (const float*)d_in[31];

    const int N_M = in_sizes[0] / D;
    const int N_C = in_sizes[1] / D;
    const int E   = in_sizes[2];
    const int EL  = in_sizes[6];
    float* out = (float*)d_out;

    uint8_t* base = (uint8_t*)d_ws;
    size_t off = 0;
    auto carve = [&](size_t bytes) -> void* {
        void* p = base + off;
        off += (bytes + 255) & ~(size_t)255;
        return p;
    };
    __half* hsA_h = (__half*)carve((size_t)N_M * 64 * 2);
    __half* hsB_h = (__half*)carve((size_t)N_C * 64 * 2);
    float2* qA    = (float2*)carve((size_t)N_M * 8);
    float2* qB    = (float2*)carve((size_t)N_C * 8);
    float2* pm_m  = (float2*)carve((size_t)N_M * 8);
    float2* pm_c  = (float2*)carve((size_t)N_C * 8);
    float* als_mc = (float*)carve((size_t)N_M * 4);
    float* ald_cm = (float*)carve((size_t)N_M * 4);
    float* als_cm = (float*)carve((size_t)N_C * 4);
    float* ald_mc = (float*)carve((size_t)N_C * 4);
    float* als2_mc = (float*)carve((size_t)N_M * 4);
    float* ald2_cm = (float*)carve((size_t)N_M * 4);
    float* als2_cm = (float*)carve((size_t)N_C * 4);
    float* ald2_mc = (float*)carve((size_t)N_C * 4);
    int* off_mc = (int*)carve((size_t)(N_C + 1) * 4);
    int* off_cm = (int*)carve((size_t)(N_M + 1) * 4);
    int* csr_mc = (int*)carve((size_t)E * 4);
    int* csr_cm = (int*)carve((size_t)E * 4);
    unsigned* pairs_mc = (unsigned*)carve((size_t)E * 4);
    unsigned* pairs_cm = (unsigned*)carve((size_t)E * 4);
    int* bcnt_base = (int*)carve(512 * 4);
    int* bcnt_mc = bcnt_base;
    int* bcnt_cm = bcnt_base + 256;
    int* bbase_mc = (int*)carve(257 * 4);
    int* bbase_cm = (int*)carve(257 * 4);
    int* bcur_mc = (int*)carve(256 * 4);
    int* bcur_cm = (int*)carve(256 * 4);
    _Float16* wp1A = (_Float16*)carve(128 * 128 * 2);
    _Float16* wp1B = (_Float16*)carve(128 * 128 * 2);
    float* Wc = (float*)carve(256 * 4);
    float* bc = (float*)carve(256);
    float* bq = (float*)carve(256);
    float2* bq2 = (float2*)bq;
    float4* foldA = (float4*)carve(64 * 16);
    float4* foldB = (float4*)carve(64 * 16);

    int shA = 0; while (((N_C + (1 << shA) - 1) >> shA) > 256) shA++;
    int shB = 0; while (((N_M + (1 << shB) - 1) >> shB) > 256) shB++;
    int nbkA = (N_C + (1 << shA) - 1) >> shA;
    int nbkB = (N_M + (1 << shB) - 1) >> shB;
    int maxN = N_M > N_C ? N_M : N_C;
    int srcbits = 1; while ((1 << srcbits) < maxN) srcbits++;

    // ---- L1: pack_w2 + decoder_prep3 + bcnt zeroing, fused ----
    prep_all<<<130, 256, 0, stream>>>(W1s_mc, W1d_cm, wp1A, W1s_cm, W1d_mc, wp1B,
                                      Wd1, bd1, Wd2, bd2, b2_cm, b2_mc,
                                      W2s_mc, a2s_mc, W2d_cm, a2d_cm,
                                      W2s_cm, a2s_cm, W2d_mc, a2d_mc,
                                      Wc, bc, bq, foldA, foldB, bcnt_base);

    // ---- L2: proj_m | proj_c | bucket_hist, fused (col-split waves, W in regs) ----
    int nbm = (N_M + 127) / 128;
    int nbc = (N_C + 127) / 128;
    int nblk = (E + 4095) / 4096;
    size_t smem_bytes = (size_t)128 * XPAD * 2 + 256 * 4;   // 18.4KB X + 1KB red
    fused_proj_hist<<<nbm + nbc + 2 * nblk, 512, smem_bytes, stream>>>(
        x_m, N_M, wp1A, a1s_mc, a1d_cm, hsA_h, als_mc, ald_cm, nbm,
        x_c, N_C, wp1B, a1s_cm, a1d_mc, hsB_h, als_cm, ald_mc, nbc,
        dst_mc, bcnt_mc, shA, dst_cm, bcnt_cm, shB, E, nblk);

    // ---- CSR build tail ----
    bucket_scan<<<1, 128, 0, stream>>>(bcnt_mc, nbkA, bbase_mc, bcur_mc, off_mc, N_C,
                                       bcnt_cm, nbkB, bbase_cm, bcur_cm, off_cm, N_M, E);
    bucket_scatter<<<2 * nblk, 256, 0, stream>>>(
        src_mc, dst_mc, bcur_mc, pairs_mc,
        src_cm, dst_cm, bcur_cm, pairs_cm, E, nblk, shA, shB, srcbits);
    bucket_expand2<<<nbkA + nbkB, 256, 0, stream>>>(
        pairs_mc, bbase_mc, N_C, off_mc, csr_mc, shA, nbkA,
        pairs_cm, bbase_cm, N_M, off_cm, csr_cm, shB, srcbits);

    int nb_c16 = (N_C + 15) / 16;
    int nb_m16 = (N_M + 15) / 16;

    // ---- Layer-1 aggregate fused with layer-2 fold ----
    gat_aggregate9f<<<nb_c16 + nb_m16, 256, 0, stream>>>(
        off_mc, csr_mc, hsA_h, als_mc, ald_mc, b1_mc, foldB, als2_cm, ald2_mc, qB, N_C,
        off_cm, csr_cm, hsB_h, als_cm, ald_cm, b1_cm, foldA, als2_mc, ald2_cm, qA, N_M,
        nb_c16);

    // ---- Layer-2 aggregate (q-table gathers) ----
    int nb_c256 = (N_C + 255) / 256;
    int nb_m256 = (N_M + 255) / 256;
    gat_aggregate10p<<<nb_c256 + nb_m256, 256, 0, stream>>>(
        off_mc, csr_mc, qA, als2_mc, ald2_mc, bq2, pm_c, N_C,
        off_cm, csr_cm, qB, als2_cm, ald2_cm, pm_m, N_M, nb_c256);

    // ---- Decoder ----
    decoder4_kernel<<<(EL + 255) / 256, 256, 0, stream>>>(rowi, coli, pm_m, pm_c, bc, out, EL);
}

// Round 31
// 193.266 us; speedup vs baseline: 1.0288x; 1.0214x over previous
//
#include <hip/hip_runtime.h>
#include <hip/hip_fp16.h>
#include <cstdint>
#include <cstddef>

typedef _Float16 f16x8 __attribute__((ext_vector_type(8)));
typedef float f32x4 __attribute__((ext_vector_type(4)));

__device__ __forceinline__ float exp_am8(float a) {
    return __builtin_amdgcn_exp2f(fmaf(a, 1.442695040888963f, -11.541560327111707f));
}

// ================= prep (fused): pack_w2 (blocks 0..127) + decoder_prep3 (128) + zero (129)
__global__ void prep_all(
    const float* __restrict__ Wa0, const float* __restrict__ Wb0, _Float16* __restrict__ P0,
    const float* __restrict__ Wa1, const float* __restrict__ Wb1, _Float16* __restrict__ P1,
    const float* __restrict__ Wd1, const float* __restrict__ bd1,
    const float* __restrict__ Wd2, const float* __restrict__ bd2,
    const float* __restrict__ b2_cm, const float* __restrict__ b2_mc,
    const float* __restrict__ W2s_mc, const float* __restrict__ a2s_mc,
    const float* __restrict__ W2d_cm, const float* __restrict__ a2d_cm,
    const float* __restrict__ W2s_cm, const float* __restrict__ a2s_cm,
    const float* __restrict__ W2d_mc, const float* __restrict__ a2d_mc,
    float* __restrict__ Wc, float* __restrict__ bc, float* __restrict__ bq,
    float4* __restrict__ foldA, float4* __restrict__ foldB,
    int* __restrict__ bcnt_base) {
    __shared__ float WcS[256];
    int b = blockIdx.x;
    int t = threadIdx.x;
    if (b < 128) {
        const float* Wa; const float* Wb; _Float16* Wp; int lb;
        if (b < 64) { Wa = Wa0; Wb = Wb0; Wp = P0; lb = b; }
        else        { Wa = Wa1; Wb = Wb1; Wp = P1; lb = b - 64; }
        constexpr int K = 128;
        constexpr int NKB = K / 32;
        int i = lb * 256 + t;
        if (i >= 128 * K) return;
        int k = i >> 7, c = i & 127;
        float v = (c < 64) ? Wa[k * 64 + c] : Wb[k * 64 + (c - 64)];
        int ct = c >> 4, lr = c & 15, kb = k >> 5, lk = (k & 31) >> 3, e = k & 7;
        Wp[((ct * NKB + kb) * 64 + (lr + 16 * lk)) * 8 + e] = (_Float16)v;
    } else if (b == 128) {
        int k = t >> 1, c = t & 1;
        float s = 0.f;
        for (int j = 0; j < 64; ++j) s += Wd1[k * 64 + j] * Wd2[j * 2 + c];
        Wc[k * 2 + c] = s;
        WcS[k * 2 + c] = s;
        if (k == 0) {
            float bv = bd2[c];
            for (int j = 0; j < 64; ++j) bv += bd1[j] * Wd2[j * 2 + c];
            bc[c] = bv;
        }
        __syncthreads();
        if (t < 2) {
            float v = 0.f;
            for (int j = 0; j < 64; ++j) v += b2_cm[j] * WcS[j * 2 + t];
            bq[t] = v;
        } else if (t < 4) {
            int cc = t - 2;
            float v = 0.f;
            for (int j = 0; j < 64; ++j) v += b2_mc[j] * WcS[(64 + j) * 2 + cc];
            bq[t] = v;
        }
        if (t < 64) {
            int j = t;
            float fa = 0.f, fd = 0.f, qx = 0.f, qy = 0.f;
            for (int cc = 0; cc < 64; ++cc) {
                float ws = W2s_mc[j * 64 + cc];
                fa += ws * a2s_mc[cc];
                qx += ws * WcS[(64 + cc) * 2 + 0];
                qy += ws * WcS[(64 + cc) * 2 + 1];
                fd += W2d_cm[j * 64 + cc] * a2d_cm[cc];
            }
            foldA[j] = make_float4(fa, fd, qx, qy);
        } else if (t < 128) {
            int j = t - 64;
            float fa = 0.f, fd = 0.f, qx = 0.f, qy = 0.f;
            for (int cc = 0; cc < 64; ++cc) {
                float ws = W2s_cm[j * 64 + cc];
                fa += ws * a2s_cm[cc];
                qx += ws * WcS[cc * 2 + 0];
                qy += ws * WcS[cc * 2 + 1];
                fd += W2d_mc[j * 64 + cc] * a2d_mc[cc];
            }
            foldB[j] = make_float4(fa, fd, qx, qy);
        }
    } else {
        bcnt_base[t] = 0;
        bcnt_base[t + 256] = 0;
    }
}

// ========== proj body v4 (512 thr): col-split waves, 4 row-tiles/block ==========
// Per block: W fragments loaded ONCE (registers), then 4 tiles of 128 rows each.
// Per tile: all 8 X loads issued together (full K=128 row in LDS), 3 barriers.
// Waves 0..3 = hs cols (write hs, reduce alpha0); waves 4..7 = hd cols (alpha1).
#define XP 136

__device__ __forceinline__ void proj_body(const float* __restrict__ X, int N,
                                          const _Float16* __restrict__ Wp,
                                          const float* __restrict__ a0v,
                                          const float* __restrict__ a1v,
                                          __half* __restrict__ out0,
                                          float* __restrict__ al0,
                                          float* __restrict__ al1,
                                          char* smem, int blk, int ntile) {
    constexpr int K = 128;
    _Float16* Xs = (_Float16*)smem;                     // [128][XP]
    float* red0 = (float*)(smem + 128 * XP * 2);        // [128]
    float* red1 = red0 + 128;                           // [128]
    int t = threadIdx.x;
    int wv = t >> 6, lane = t & 63, lr = lane & 15, lk = lane >> 4;
    int xrow = t >> 4;          // 32 rows per pass, 16 threads/row
    int xcp = t & 15;           // float4 index within 256B row-half

    // per-wave W fragments for col tile wv (4 x f16x8 in registers)
    f16x8 wfr[4];
#pragma unroll
    for (int kbb = 0; kbb < 4; ++kbb)
        wfr[kbb] = ((const f16x8*)Wp)[(wv * 4 + kbb) * 64 + lane];

    bool is_s = wv < 4;
    float4 aq = is_s ? ((const float4*)a0v)[wv * 4 + lk]
                     : ((const float4*)a1v)[(wv - 4) * 4 + lk];
    float* red = is_s ? red0 : red1;

    for (int tile = 0; tile < ntile; ++tile) {
        int rt = (blk * ntile + tile) * 128;
        if (rt >= N) break;
        // issue all 8 loads (both K-halves, 4 row-passes) -> max MLP
        float4 v[8];
#pragma unroll
        for (int p = 0; p < 4; ++p) {
            int grow = rt + p * 32 + xrow;
            if (grow >= N) grow = N - 1;
            const float* rp = X + (size_t)grow * K + xcp * 4;
            v[p] = *(const float4*)rp;
            v[4 + p] = *(const float4*)(rp + 64);
        }
        __syncthreads();   // prev tile's Xs reads + red reads complete
#pragma unroll
        for (int p = 0; p < 4; ++p) {
            int r = p * 32 + xrow;
            __half2 h01 = __floats2half2_rn(v[p].x, v[p].y);
            __half2 h23 = __floats2half2_rn(v[p].z, v[p].w);
            uint2 pk;
            pk.x = *(const unsigned int*)&h01;
            pk.y = *(const unsigned int*)&h23;
            *(uint2*)&Xs[r * XP + xcp * 4] = pk;
            h01 = __floats2half2_rn(v[4 + p].x, v[4 + p].y);
            h23 = __floats2half2_rn(v[4 + p].z, v[4 + p].w);
            pk.x = *(const unsigned int*)&h01;
            pk.y = *(const unsigned int*)&h23;
            *(uint2*)&Xs[r * XP + 64 + xcp * 4] = pk;
        }
        if (t < 128) { red0[t] = 0.f; red1[t] = 0.f; }
        __syncthreads();
        f32x4 acc[8];
#pragma unroll
        for (int i = 0; i < 8; ++i) acc[i] = f32x4{0.f, 0.f, 0.f, 0.f};
#pragma unroll
        for (int rt8 = 0; rt8 < 8; ++rt8) {
#pragma unroll
            for (int kbb = 0; kbb < 4; ++kbb) {
                f16x8 bf = *(const f16x8*)&Xs[(rt8 * 16 + lr) * XP + kbb * 32 + lk * 8];
                acc[rt8] = __builtin_amdgcn_mfma_f32_16x16x32_f16(
                    wfr[kbb], bf, acc[rt8], 0, 0, 0);
            }
        }
        // epilogue (v3b-verified role split)
#pragma unroll
        for (int rt8 = 0; rt8 < 8; ++rt8) {
            f32x4 vv = acc[rt8];
            float p = vv[0] * aq.x + vv[1] * aq.y + vv[2] * aq.z + vv[3] * aq.w;
            p += __shfl_xor(p, 16); p += __shfl_xor(p, 32);
            if (lane < 16) atomicAdd(&red[rt8 * 16 + lr], p);
            int row = rt + rt8 * 16 + lr;
            if (is_s && row < N) {
                __half2 h01 = __floats2half2_rn(vv[0], vv[1]);
                __half2 h23 = __floats2half2_rn(vv[2], vv[3]);
                uint2 pk;
                pk.x = *(const unsigned int*)&h01;
                pk.y = *(const unsigned int*)&h23;
                *(uint2*)(out0 + ((size_t)row << 6) + wv * 16 + lk * 4) = pk;
            }
        }
        __syncthreads();
        if (t < 128) {
            int row = rt + t;
            if (row < N) { al0[row] = red0[t]; al1[row] = red1[t]; }
        }
    }
}

// ========== fused launch (512 thr): proj_m | proj_c | bucket_hist ==========
__global__ __launch_bounds__(512) void fused_proj_hist(
    const float* __restrict__ Xm, int Nm, const _Float16* __restrict__ WpA,
    const float* __restrict__ a0A, const float* __restrict__ a1A,
    __half* __restrict__ outA, float* __restrict__ al0A, float* __restrict__ al1A, int nbm,
    const float* __restrict__ Xc, int Nc, const _Float16* __restrict__ WpB,
    const float* __restrict__ a0B, const float* __restrict__ a1B,
    __half* __restrict__ outB, float* __restrict__ al0B, float* __restrict__ al1B, int nbc,
    const int* __restrict__ dmc, int* __restrict__ bcnt_mc, int shA,
    const int* __restrict__ dcm, int* __restrict__ bcnt_cm, int shB, int E, int nblk,
    int ntile) {
    extern __shared__ __align__(16) char smem[];
    int b = blockIdx.x;
    if (b < nbm) {
        proj_body(Xm, Nm, WpA, a0A, a1A, outA, al0A, al1A, smem, b, ntile);
        return;
    }
    b -= nbm;
    if (b < nbc) {
        proj_body(Xc, Nc, WpB, a0B, a1B, outB, al0B, al1B, smem, b, ntile);
        return;
    }
    b -= nbc;
    int* h = (int*)smem;
    const int* dst; int* bcnt; int sh; int base;
    if (b < nblk) { dst = dmc; bcnt = bcnt_mc; sh = shA; base = b * 4096; }
    else { dst = dcm; bcnt = bcnt_cm; sh = shB; base = (b - nblk) * 4096; }
    int t = threadIdx.x;
    if (t < 256) h[t] = 0;
    __syncthreads();
#pragma unroll
    for (int j = 0; j < 8; ++j) {
        int i = base + j * 512 + t;
        if (i < E) atomicAdd(&h[dst[i] >> sh], 1);
    }
    __syncthreads();
    if (t < 256) {
        int c = h[t];
        if (c > 0) atomicAdd(&bcnt[t], c);
    }
}

// ================= CSR build tail =================
__global__ void bucket_scan(const int* __restrict__ bcntA, int nbkA,
                            int* __restrict__ bbaseA, int* __restrict__ bcurA,
                            int* __restrict__ offA, int nA,
                            const int* __restrict__ bcntB, int nbkB,
                            int* __restrict__ bbaseB, int* __restrict__ bcurB,
                            int* __restrict__ offB, int nB, int E) {
    int t = threadIdx.x;
    if (t == 0) {
        int run = 0;
        for (int i = 0; i < nbkA; ++i) { bbaseA[i] = run; bcurA[i] = run; run += bcntA[i]; }
        bbaseA[nbkA] = run;
        offA[nA] = E;
    }
    if (t == 64) {
        int run = 0;
        for (int i = 0; i < nbkB; ++i) { bbaseB[i] = run; bcurB[i] = run; run += bcntB[i]; }
        bbaseB[nbkB] = run;
        offB[nB] = E;
    }
}

__global__ __launch_bounds__(256) void bucket_scatter(
    const int* __restrict__ srcA, const int* __restrict__ dstA,
    int* __restrict__ bcurA, unsigned* __restrict__ pairsA,
    const int* __restrict__ srcB, const int* __restrict__ dstB,
    int* __restrict__ bcurB, unsigned* __restrict__ pairsB,
    int E, int nblkA, int shA, int shB, int srcbits) {
    __shared__ int bcnt[256];
    __shared__ int bbase[256];
    const int* src; const int* dst; int* bcur; unsigned* pairs; int sh; int base;
    if ((int)blockIdx.x < nblkA) {
        src = srcA; dst = dstA; bcur = bcurA; pairs = pairsA; sh = shA;
        base = blockIdx.x * 4096;
    } else {
        src = srcB; dst = dstB; bcur = bcurB; pairs = pairsB; sh = shB;
        base = (blockIdx.x - nblkA) * 4096;
    }
    int t = threadIdx.x;
    int msk = (1 << sh) - 1;
    bcnt[t] = 0;
    __syncthreads();
    int sreg[16], dreg[16];
#pragma unroll
    for (int j = 0; j < 16; ++j) {
        int i = base + j * 256 + t;
        if (i < E) {
            sreg[j] = src[i];
            dreg[j] = dst[i];
            atomicAdd(&bcnt[dreg[j] >> sh], 1);
        } else {
            dreg[j] = -1;
        }
    }
    __syncthreads();
    {
        int c = bcnt[t];
        int g = (c > 0) ? atomicAdd(&bcur[t], c) : 0;
        bbase[t] = g;
        bcnt[t] = 0;
    }
    __syncthreads();
#pragma unroll
    for (int j = 0; j < 16; ++j) {
        if (dreg[j] >= 0) {
            int b = dreg[j] >> sh;
            int r = atomicAdd(&bcnt[b], 1);
            pairs[bbase[b] + r] = ((unsigned)(dreg[j] & msk) << srcbits) | (unsigned)sreg[j];
        }
    }
}

__global__ __launch_bounds__(256) void bucket_expand2(
    const unsigned* __restrict__ pairsA, const int* __restrict__ bbaseA, int nA,
    int* __restrict__ offA, int* __restrict__ csrA, int shA, int nbA,
    const unsigned* __restrict__ pairsB, const int* __restrict__ bbaseB, int nB,
    int* __restrict__ offB, int* __restrict__ csrB, int shB, int srcbits) {
    __shared__ int lcnt[1024];
    __shared__ int red[256];
    const unsigned* pairs; const int* bbase; int n; int* off; int* csr; int sh; int b;
    if ((int)blockIdx.x < nbA) {
        pairs = pairsA; bbase = bbaseA; n = nA; off = offA; csr = csrA; sh = shA;
        b = blockIdx.x;
    } else {
        pairs = pairsB; bbase = bbaseB; n = nB; off = offB; csr = csrB; sh = shB;
        b = blockIdx.x - nbA;
    }
    int dpb = 1 << sh;
    int d0 = b << sh;
    int t = threadIdx.x;
    unsigned smask = (1u << srcbits) - 1u;
    for (int dl = t; dl < dpb; dl += 256) lcnt[dl] = 0;
    __syncthreads();
    int pbeg = bbase[b], pend = bbase[b + 1];
    for (int i = pbeg + t; i < pend; i += 256)
        atomicAdd(&lcnt[pairs[i] >> srcbits], 1);
    __syncthreads();
    int per = (dpb + 255) >> 8;
    int i0 = t * per;
    int s = 0;
    for (int j = 0; j < per; ++j) {
        int dl = i0 + j;
        if (dl < dpb) s += lcnt[dl];
    }
    red[t] = s;
    __syncthreads();
    for (int st = 1; st < 256; st <<= 1) {
        int tmp = (t >= st) ? red[t - st] : 0;
        __syncthreads();
        red[t] += tmp;
        __syncthreads();
    }
    int run = pbeg + red[t] - s;
    for (int j = 0; j < per; ++j) {
        int dl = i0 + j;
        if (dl < dpb) {
            int c = lcnt[dl];
            if (d0 + dl < n) off[d0 + dl] = run;
            lcnt[dl] = run;
            run += c;
        }
    }
    __syncthreads();
    for (int i = pbeg + t; i < pend; i += 256) {
        unsigned p = pairs[i];
        int dl = (int)(p >> srcbits);
        int pos = atomicAdd(&lcnt[dl], 1);
        csr[pos] = (int)(p & smask);
    }
}

// ========== GAT aggregation v9f (layer 1, FUSED fold epilogue) ==========
#define AGG_CAP 64
#define AGG_PAD 66

__global__ __launch_bounds__(256) void gat_aggregate9f(
    const int* __restrict__ off0, const int* __restrict__ csr0,
    const __half* __restrict__ hs0, const float* __restrict__ als0,
    const float* __restrict__ ald0, const float* __restrict__ bias0,
    const float4* __restrict__ fold0, float* __restrict__ als2_0,
    float* __restrict__ ald2_0, float2* __restrict__ q2_0, int n0,
    const int* __restrict__ off1, const int* __restrict__ csr1,
    const __half* __restrict__ hs1, const float* __restrict__ als1,
    const float* __restrict__ ald1, const float* __restrict__ bias1,
    const float4* __restrict__ fold1, float* __restrict__ als2_1,
    float* __restrict__ ald2_1, float2* __restrict__ q2_1, int n1,
    int nb0) {
    __shared__ uint2 wP[16][AGG_PAD];
    int t = threadIdx.x;
    int slot = t >> 4;
    int sub = t & 15;

    const int* off; const int* csr; const __half* hs; const float* als;
    const float* ald; const float* bias; const float4* fold;
    float* als2; float* ald2; float2* q2; int nd; int b;
    if (blockIdx.x < (unsigned)nb0) {
        b = blockIdx.x;
        off = off0; csr = csr0; hs = hs0; als = als0; ald = ald0; bias = bias0;
        fold = fold0; als2 = als2_0; ald2 = ald2_0; q2 = q2_0; nd = n0;
    } else {
        b = blockIdx.x - nb0;
        off = off1; csr = csr1; hs = hs1; als = als1; ald = ald1; bias = bias1;
        fold = fold1; als2 = als2_1; ald2 = ald2_1; q2 = q2_1; nd = n1;
    }
    int d = b * 16 + slot;
    bool active = d < nd;
    int beg = 0, deg = 0;
    float aldv = 0.f;
    if (active) {
        beg = off[d];
        deg = off[d + 1] - beg;
        aldv = ald[d];
    }
    float4 bl4 = ((const float4*)bias)[sub];
    uint2* WP = wP[slot];

    float sum = 0.f;
    for (int i = sub; i < deg; i += 16) {
        int s = csr[beg + i];
        float a = als[s] + aldv;
        a = (a >= 0.f) ? a : 0.2f * a;
        float w = exp_am8(a);
        sum += w;
        if (i < AGG_CAP) {
            __half hw = __float2half_rn(w);
            __half2 h2 = __half2half2(hw);
            WP[i] = make_uint2(*(const unsigned int*)&h2, (unsigned int)s);
        }
    }
    sum += __shfl_xor(sum, 1);
    sum += __shfl_xor(sum, 2);
    sum += __shfl_xor(sum, 4);
    sum += __shfl_xor(sum, 8);
    float inv = 1.f / fmaxf(sum, 1e-16f);

    int dc = deg < AGG_CAP ? deg : AGG_CAP;
    const uint2* hs4 = (const uint2*)hs;
    __half2 z = __floats2half2_rn(0.f, 0.f);
    __half2 aA = z, aB = z, aC = z, aD = z;
    int i = 0;
    for (; i + 8 <= dc; i += 8) {
        uint4 q0 = *(const uint4*)&WP[i];
        uint4 q1 = *(const uint4*)&WP[i + 2];
        uint4 q2r = *(const uint4*)&WP[i + 4];
        uint4 q3 = *(const uint4*)&WP[i + 6];
        uint2 v0 = hs4[(size_t)q0.y * 16 + sub];
        uint2 v1 = hs4[(size_t)q0.w * 16 + sub];
        uint2 v2 = hs4[(size_t)q1.y * 16 + sub];
        uint2 v3 = hs4[(size_t)q1.w * 16 + sub];
        uint2 v4 = hs4[(size_t)q2r.y * 16 + sub];
        uint2 v5 = hs4[(size_t)q2r.w * 16 + sub];
        uint2 v6 = hs4[(size_t)q3.y * 16 + sub];
        uint2 v7 = hs4[(size_t)q3.w * 16 + sub];
        aA = __hfma2(*(const __half2*)&q0.x, *(const __half2*)&v0.x, aA);
        aB = __hfma2(*(const __half2*)&q0.x, *(const __half2*)&v0.y, aB);
        aC = __hfma2(*(const __half2*)&q0.z, *(const __half2*)&v1.x, aC);
        aD = __hfma2(*(const __half2*)&q0.z, *(const __half2*)&v1.y, aD);
        aA = __hfma2(*(const __half2*)&q1.x, *(const __half2*)&v2.x, aA);
        aB = __hfma2(*(const __half2*)&q1.x, *(const __half2*)&v2.y, aB);
        aC = __hfma2(*(const __half2*)&q1.z, *(const __half2*)&v3.x, aC);
        aD = __hfma2(*(const __half2*)&q1.z, *(const __half2*)&v3.y, aD);
        aA = __hfma2(*(const __half2*)&q2r.x, *(const __half2*)&v4.x, aA);
        aB = __hfma2(*(const __half2*)&q2r.x, *(const __half2*)&v4.y, aB);
        aC = __hfma2(*(const __half2*)&q2r.z, *(const __half2*)&v5.x, aC);
        aD = __hfma2(*(const __half2*)&q2r.z, *(const __half2*)&v5.y, aD);
        aA = __hfma2(*(const __half2*)&q3.x, *(const __half2*)&v6.x, aA);
        aB = __hfma2(*(const __half2*)&q3.x, *(const __half2*)&v6.y, aB);
        aC = __hfma2(*(const __half2*)&q3.z, *(const __half2*)&v7.x, aC);
        aD = __hfma2(*(const __half2*)&q3.z, *(const __half2*)&v7.y, aD);
    }
    for (; i + 2 <= dc; i += 2) {
        uint4 q = *(const uint4*)&WP[i];
        uint2 v0 = hs4[(size_t)q.y * 16 + sub];
        uint2 v1 = hs4[(size_t)q.w * 16 + sub];
        aA = __hfma2(*(const __half2*)&q.x, *(const __half2*)&v0.x, aA);
        aB = __hfma2(*(const __half2*)&q.x, *(const __half2*)&v0.y, aB);
        aC = __hfma2(*(const __half2*)&q.z, *(const __half2*)&v1.x, aC);
        aD = __hfma2(*(const __half2*)&q.z, *(const __half2*)&v1.y, aD);
    }
    if (i < dc) {
        uint2 u = WP[i];
        uint2 v = hs4[(size_t)u.y * 16 + sub];
        aA = __hfma2(*(const __half2*)&u.x, *(const __half2*)&v.x, aA);
        aB = __hfma2(*(const __half2*)&u.x, *(const __half2*)&v.y, aB);
    }
    for (int j = AGG_CAP; j < deg; ++j) {
        int s = csr[beg + j];
        float a = als[s] + aldv;
        a = (a >= 0.f) ? a : 0.2f * a;
        __half hw = __float2half_rn(exp_am8(a));
        __half2 w2 = __half2half2(hw);
        uint2 v = hs4[(size_t)s * 16 + sub];
        aA = __hfma2(w2, *(const __half2*)&v.x, aA);
        aB = __hfma2(w2, *(const __half2*)&v.y, aB);
    }
    float2 fA = __half22float2(aA);
    float2 fB = __half22float2(aB);
    float2 fC = __half22float2(aC);
    float2 fD = __half22float2(aD);
    float o0 = (fA.x + fC.x) * inv + bl4.x;
    float o1 = (fA.y + fC.y) * inv + bl4.y;
    float o2 = (fB.x + fD.x) * inv + bl4.z;
    float o3 = (fB.y + fD.y) * inv + bl4.w;
    if (deg == 0) { o0 = bl4.x; o1 = bl4.y; o2 = bl4.z; o3 = bl4.w; }
    o0 = fmaxf(o0, 0.f); o1 = fmaxf(o1, 0.f);
    o2 = fmaxf(o2, 0.f); o3 = fmaxf(o3, 0.f);

    float4 f0 = fold[4 * sub + 0];
    float4 f1 = fold[4 * sub + 1];
    float4 f2 = fold[4 * sub + 2];
    float4 f3 = fold[4 * sub + 3];
    float a0 = o0 * f0.x + o1 * f1.x + o2 * f2.x + o3 * f3.x;
    float a1 = o0 * f0.y + o1 * f1.y + o2 * f2.y + o3 * f3.y;
    float a2 = o0 * f0.z + o1 * f1.z + o2 * f2.z + o3 * f3.z;
    float a3 = o0 * f0.w + o1 * f1.w + o2 * f2.w + o3 * f3.w;
#pragma unroll
    for (int o = 1; o < 16; o <<= 1) {
        a0 += __shfl_xor(a0, o);
        a1 += __shfl_xor(a1, o);
        a2 += __shfl_xor(a2, o);
        a3 += __shfl_xor(a3, o);
    }
    if (active && sub == 0) {
        als2[d] = a0;
        ald2[d] = a1;
        q2[d] = make_float2(a2, a3);
    }
}

// ========== GAT aggregation v10 (layer 2): one dst per LANE, q-table gathers ==========
__global__ __launch_bounds__(256) void gat_aggregate10p(
    const int* __restrict__ off0, const int* __restrict__ csr0,
    const float2* __restrict__ q0, const float* __restrict__ als0,
    const float* __restrict__ ald0, const float2* __restrict__ bqp,
    float2* __restrict__ out0, int n0,
    const int* __restrict__ off1, const int* __restrict__ csr1,
    const float2* __restrict__ q1, const float* __restrict__ als1,
    const float* __restrict__ ald1,
    float2* __restrict__ out1, int n1,
    int nb0) {
    const int* off; const int* csr; const float2* qt; const float* als;
    const float* ald; float2 bq; float2* outp; int nd; int b;
    if (blockIdx.x < (unsigned)nb0) {
        b = blockIdx.x;
        off = off0; csr = csr0; qt = q0; als = als0; ald = ald0; bq = bqp[1];
        outp = out0; nd = n0;
    } else {
        b = blockIdx.x - nb0;
        off = off1; csr = csr1; qt = q1; als = als1; ald = ald1; bq = bqp[0];
        outp = out1; nd = n1;
    }
    int d = b * 256 + threadIdx.x;
    if (d >= nd) return;
    int beg = off[d], end = off[d + 1];
    float aldv = ald[d];
    float sum = 0.f, ax = 0.f, ay = 0.f;
    int i = beg;
    for (; i + 2 <= end; i += 2) {
        int s0 = csr[i], s1 = csr[i + 1];
        float a0 = als[s0] + aldv;
        float a1 = als[s1] + aldv;
        float2 v0 = qt[s0];
        float2 v1 = qt[s1];
        a0 = (a0 >= 0.f) ? a0 : 0.2f * a0;
        a1 = (a1 >= 0.f) ? a1 : 0.2f * a1;
        float w0 = exp_am8(a0);
        float w1 = exp_am8(a1);
        sum += w0 + w1;
        ax = fmaf(w0, v0.x, ax); ay = fmaf(w0, v0.y, ay);
        ax = fmaf(w1, v1.x, ax); ay = fmaf(w1, v1.y, ay);
    }
    if (i < end) {
        int s = csr[i];
        float a = als[s] + aldv;
        a = (a >= 0.f) ? a : 0.2f * a;
        float w = exp_am8(a);
        float2 v = qt[s];
        sum += w;
        ax = fmaf(w, v.x, ax); ay = fmaf(w, v.y, ay);
    }
    float inv = 1.f / fmaxf(sum, 1e-16f);
    outp[d] = make_float2(ax * inv + bq.x, ay * inv + bq.y);
}

// ---------------- decoder v4: out[e] = pm[row] + pc[col] + bc ----------------
__global__ __launch_bounds__(256) void decoder4_kernel(const int* __restrict__ row,
                                                       const int* __restrict__ col,
                                                       const float2* __restrict__ pm,
                                                       const float2* __restrict__ pc,
                                                       const float* __restrict__ bc,
                                                       float* __restrict__ out, int EL) {
    int e = blockIdx.x * 256 + threadIdx.x;
    if (e >= EL) return;
    float2 a = pm[row[e]];
    float2 b = pc[col[e]];
    *(float2*)(out + 2 * (size_t)e) = make_float2(a.x + b.x + bc[0], a.y + b.y + bc[1]);
}

// ---------------- launch ----------------
extern "C" void kernel_launch(void* const* d_in, const int* in_sizes, int n_in,
                              void* d_out, int out_size, void* d_ws, size_t ws_size,
                              hipStream_t stream) {
    const int D = 128;
    const float* x_m    = (const float*)d_in[0];
    const float* x_c    = (const float*)d_in[1];
    const int*   src_mc = (const int*)d_in[2];
    const int*   dst_mc = (const int*)d_in[3];
    const int*   src_cm = (const int*)d_in[4];
    const int*   dst_cm = (const int*)d_in[5];
    const int*   rowi   = (const int*)d_in[6];
    const int*   coli   = (const int*)d_in[7];
    const float* W1s_mc = (const float*)d_in[8];
    const float* W1d_mc = (const float*)d_in[9];
    const float* a1s_mc = (const float*)d_in[10];
    const float* a1d_mc = (const float*)d_in[11];
    const float* b1_mc  = (const float*)d_in[12];
    const float* W1s_cm = (const float*)d_in[13];
    const float* W1d_cm = (const float*)d_in[14];
    const float* a1s_cm = (const float*)d_in[15];
    const float* a1d_cm = (const float*)d_in[16];
    const float* b1_cm  = (const float*)d_in[17];
    const float* W2s_mc = (const float*)d_in[18];
    const float* W2d_mc = (const float*)d_in[19];
    const float* a2s_mc = (const float*)d_in[20];
    const float* a2d_mc = (const float*)d_in[21];
    const float* b2_mc  = (const float*)d_in[22];
    const float* W2s_cm = (const float*)d_in[23];
    const float* W2d_cm = (const float*)d_in[24];
    const float* a2s_cm = (const float*)d_in[25];
    const float* a2d_cm = (const float*)d_in[26];
    const float* b2_cm  = (const float*)d_in[27];
    const float* Wd1    = (const float*)d_in[28];
    const float* bd1    = (const float*)d_in[29];
    const float* Wd2    = (const float*)d_in[30];
    const float* bd2    = (const float*)d_in[31];

    const int N_M = in_sizes[0] / D;
    const int N_C = in_sizes[1] / D;
    const int E   = in_sizes[2];
    const int EL  = in_sizes[6];
    float* out = (float*)d_out;

    uint8_t* base = (uint8_t*)d_ws;
    size_t off = 0;
    auto carve = [&](size_t bytes) -> void* {
        void* p = base + off;
        off += (bytes + 255) & ~(size_t)255;
        return p;
    };
    __half* hsA_h = (__half*)carve((size_t)N_M * 64 * 2);
    __half* hsB_h = (__half*)carve((size_t)N_C * 64 * 2);
    float2* qA    = (float2*)carve((size_t)N_M * 8);
    float2* qB    = (float2*)carve((size_t)N_C * 8);
    float2* pm_m  = (float2*)carve((size_t)N_M * 8);
    float2* pm_c  = (float2*)carve((size_t)N_C * 8);
    float* als_mc = (float*)carve((size_t)N_M * 4);
    float* ald_cm = (float*)carve((size_t)N_M * 4);
    float* als_cm = (float*)carve((size_t)N_C * 4);
    float* ald_mc = (float*)carve((size_t)N_C * 4);
    float* als2_mc = (float*)carve((size_t)N_M * 4);
    float* ald2_cm = (float*)carve((size_t)N_M * 4);
    float* als2_cm = (float*)carve((size_t)N_C * 4);
    float* ald2_mc = (float*)carve((size_t)N_C * 4);
    int* off_mc = (int*)carve((size_t)(N_C + 1) * 4);
    int* off_cm = (int*)carve((size_t)(N_M + 1) * 4);
    int* csr_mc = (int*)carve((size_t)E * 4);
    int* csr_cm = (int*)carve((size_t)E * 4);
    unsigned* pairs_mc = (unsigned*)carve((size_t)E * 4);
    unsigned* pairs_cm = (unsigned*)carve((size_t)E * 4);
    int* bcnt_base = (int*)carve(512 * 4);
    int* bcnt_mc = bcnt_base;
    int* bcnt_cm = bcnt_base + 256;
    int* bbase_mc = (int*)carve(257 * 4);
    int* bbase_cm = (int*)carve(257 * 4);
    int* bcur_mc = (int*)carve(256 * 4);
    int* bcur_cm = (int*)carve(256 * 4);
    _Float16* wp1A = (_Float16*)carve(128 * 128 * 2);
    _Float16* wp1B = (_Float16*)carve(128 * 128 * 2);
    float* Wc = (float*)carve(256 * 4);
    float* bc = (float*)carve(256);
    float* bq = (float*)carve(256);
    float2* bq2 = (float2*)bq;
    float4* foldA = (float4*)carve(64 * 16);
    float4* foldB = (float4*)carve(64 * 16);

    int shA = 0; while (((N_C + (1 << shA) - 1) >> shA) > 256) shA++;
    int shB = 0; while (((N_M + (1 << shB) - 1) >> shB) > 256) shB++;
    int nbkA = (N_C + (1 << shA) - 1) >> shA;
    int nbkB = (N_M + (1 << shB) - 1) >> shB;
    int maxN = N_M > N_C ? N_M : N_C;
    int srcbits = 1; while ((1 << srcbits) < maxN) srcbits++;

    // ---- L1: pack_w2 + decoder_prep3 + bcnt zeroing, fused ----
    prep_all<<<130, 256, 0, stream>>>(W1s_mc, W1d_cm, wp1A, W1s_cm, W1d_mc, wp1B,
                                      Wd1, bd1, Wd2, bd2, b2_cm, b2_mc,
                                      W2s_mc, a2s_mc, W2d_cm, a2d_cm,
                                      W2s_cm, a2s_cm, W2d_mc, a2d_mc,
                                      Wc, bc, bq, foldA, foldB, bcnt_base);

    // ---- L2: proj_m | proj_c | bucket_hist, fused (4 row-tiles/block) ----
    const int NTILE = 4;
    int nbm = (N_M + 128 * NTILE - 1) / (128 * NTILE);
    int nbc = (N_C + 128 * NTILE - 1) / (128 * NTILE);
    int nblk = (E + 4095) / 4096;
    size_t smem_bytes = (size_t)128 * XP * 2 + 256 * 4;   // 34KB X + 1KB red
    fused_proj_hist<<<nbm + nbc + 2 * nblk, 512, smem_bytes, stream>>>(
        x_m, N_M, wp1A, a1s_mc, a1d_cm, hsA_h, als_mc, ald_cm, nbm,
        x_c, N_C, wp1B, a1s_cm, a1d_mc, hsB_h, als_cm, ald_mc, nbc,
        dst_mc, bcnt_mc, shA, dst_cm, bcnt_cm, shB, E, nblk, NTILE);

    // ---- CSR build tail ----
    bucket_scan<<<1, 128, 0, stream>>>(bcnt_mc, nbkA, bbase_mc, bcur_mc, off_mc, N_C,
                                       bcnt_cm, nbkB, bbase_cm, bcur_cm, off_cm, N_M, E);
    bucket_scatter<<<2 * nblk, 256, 0, stream>>>(
        src_mc, dst_mc, bcur_mc, pairs_mc,
        src_cm, dst_cm, bcur_cm, pairs_cm, E, nblk, shA, shB, srcbits);
    bucket_expand2<<<nbkA + nbkB, 256, 0, stream>>>(
        pairs_mc, bbase_mc, N_C, off_mc, csr_mc, shA, nbkA,
        pairs_cm, bbase_cm, N_M, off_cm, csr_cm, shB, srcbits);

    int nb_c16 = (N_C + 15) / 16;
    int nb_m16 = (N_M + 15) / 16;

    // ---- Layer-1 aggregate fused with layer-2 fold ----
    gat_aggregate9f<<<nb_c16 + nb_m16, 256, 0, stream>>>(
        off_mc, csr_mc, hsA_h, als_mc, ald_mc, b1_mc, foldB, als2_cm, ald2_mc, qB, N_C,
        off_cm, csr_cm, hsB_h, als_cm, ald_cm, b1_cm, foldA, als2_mc, ald2_cm, qA, N_M,
        nb_c16);

    // ---- Layer-2 aggregate (q-table gathers) ----
    int nb_c256 = (N_C + 255) / 256;
    int nb_m256 = (N_M + 255) / 256;
    gat_aggregate10p<<<nb_c256 + nb_m256, 256, 0, stream>>>(
        off_mc, csr_mc, qA, als2_mc, ald2_mc, bq2, pm_c, N_C,
        off_cm, csr_cm, qB, als2_cm, ald2_cm, pm_m, N_M, nb_c256);

    // ---- Decoder ----
    decoder4_kernel<<<(EL + 255) / 256, 256, 0, stream>>>(rowi, coli, pm_m, pm_c, bc, out, EL);
}